// Round 6
// baseline (310.799 us; speedup 1.0000x reference)
//
#include <hip/hip_runtime.h>
#include <hip/hip_bf16.h>
#include <math.h>

// S4DConv via MFMA: B=8, L=2048, H=512, N=64, CH=1
//   A u-rows [4096][2048], k-rows [512][2048]  (bf16)
//   U[4608][4096] = A x B1^T : u-rows via 256^2 8-phase GEMM (k_fwd8),
//                              k-rows via small 128^2 GEMM (k_kfg)
//   Ys = scale * (KF * U) complex -> bf16                            [k_mix]
//   y[bh][t] = Ys x T2^T, K=4096 split-K=2, 8-phase (k_inv8) + combine

namespace {
constexpr int cB = 8;
constexpr int cL = 2048;
constexpr int cH = 512;
constexpr int cN = 64;
constexpr int M1 = 4095;
constexpr int M2 = 4096;
constexpr int BH = cB * cH;            // 4096
constexpr int MA = BH + cH;            // 4608

// float region
constexpr size_t WS_MODES = 0;                        // [H][N][6]
// short regions
constexpr size_t S0   = 2 * ((size_t)cH * cN * 6);
constexpr size_t S_B1 = S0;                           // [4096][2048]
constexpr size_t S_A  = S_B1 + (size_t)4096 * 2048;   // [4608][2048]
constexpr size_t S_T2 = S_A  + (size_t)MA * 2048;     // [2048][4096]
constexpr size_t S_U  = S_T2 + (size_t)2048 * 4096;   // [4608][4096]; P1 (fp32 [4096][2048]) overlays after k_mix
constexpr size_t S_YS = S0;                           // overlay [4096][4096]
}

typedef __attribute__((ext_vector_type(8))) short short8;
typedef __attribute__((ext_vector_type(4))) float f32x4;

static __device__ inline short f2bf(float x) {
    __hip_bfloat16 h = __float2bfloat16(x);
    return *reinterpret_cast<short*>(&h);
}
static __device__ inline float bf2f(short s) {
    return __uint_as_float(((unsigned int)(unsigned short)s) << 16);
}
static __device__ __forceinline__ void load_lds16(const short* g, short* l) {
    __builtin_amdgcn_global_load_lds(
        (const __attribute__((address_space(1))) void*)g,
        (__attribute__((address_space(3))) void*)l, 16, 0, 0);
}
#define WAIT_LGKM0() do { asm volatile("s_waitcnt lgkmcnt(0)" ::: "memory"); \
                          __builtin_amdgcn_sched_barrier(0); } while (0)
#define WAIT_VM(n)   do { asm volatile("s_waitcnt vmcnt(" #n ")" ::: "memory"); \
                          __builtin_amdgcn_sched_barrier(0); } while (0)

__global__ __launch_bounds__(256) void k_precomp(
    const float* __restrict__ w_re, const float* __restrict__ w_im,
    const float* __restrict__ C_re, const float* __restrict__ C_im,
    const float* __restrict__ dt, float* __restrict__ W)
{
    int idx = blockIdx.x * 256 + threadIdx.x;
    if (idx >= cH * cN) return;
    int h = idx / cN;
    double dtv = dt[h];
    double wr = w_re[idx], wi = w_im[idx];
    double ar = wr * dtv, ai = wi * dtv;
    double er = exp(ar);
    double zs, zc; sincos(ai, &zs, &zc);
    double zr = er * zc, zi = er * zs;
    double nr = zr - 1.0, ni = zi;
    double inv = 1.0 / (wr * wr + wi * wi);
    double gr = (nr * wr + ni * wi) * inv;
    double gi = (ni * wr - nr * wi) * inv;
    double cr = C_re[idx], ci = C_im[idx];
    double csr = cr * gr - ci * gi, csi = cr * gi + ci * gr;
    float* m = W + WS_MODES + (size_t)idx * 6;
    m[0] = (float)csr; m[1] = (float)csi;
    m[2] = (float)zr;  m[3] = (float)zi;
    m[4] = (float)ar;  m[5] = (float)ai;
}

__global__ __launch_bounds__(256) void k_tab1(short* __restrict__ Wb)
{
    int g = blockIdx.x * 256 + threadIdx.x;
    int j = g >> 11, t = g & 2047;
    int p = (j * t) % M1;
    float s, c;
    sincosf((6.283185307179586f / (float)M1) * (float)p, &s, &c);
    Wb[S_B1 + (size_t)j * 2048 + t]          = f2bf(c);
    Wb[S_B1 + (size_t)(2048 + j) * 2048 + t] = f2bf(s);
}

__global__ __launch_bounds__(256) void k_tab2(short* __restrict__ Wb)
{
    int g = blockIdx.x * 256 + threadIdx.x;
    int t = g >> 11, j = g & 2047;
    int p = (t * j) & (M2 - 1);
    float s, c;
    sincosf((6.283185307179586f / (float)M2) * (float)p, &s, &c);
    Wb[S_T2 + (size_t)t * 4096 + j]        = f2bf(c);
    Wb[S_T2 + (size_t)t * 4096 + 2048 + j] = f2bf(s);
}

__global__ __launch_bounds__(256) void k_trans(const float* __restrict__ u,
                                               short* __restrict__ Wb)
{
    __shared__ float tile[64][65];
    int t0 = blockIdx.x * 64;
    int h0 = blockIdx.y * 64;
    int b  = blockIdx.z;
    int cx = threadIdx.x & 63, r0 = threadIdx.x >> 6;
#pragma unroll
    for (int i = 0; i < 16; ++i) {
        int row = r0 + i * 4;
        tile[row][cx] = u[((size_t)b * cL + t0 + row) * cH + h0 + cx];
    }
    __syncthreads();
    short* A = Wb + S_A;
#pragma unroll
    for (int i = 0; i < 16; ++i) {
        int hrow = r0 + i * 4;
        A[(size_t)(b * cH + h0 + hrow) * 2048 + t0 + cx] = f2bf(tile[cx][hrow]);
    }
}

__global__ __launch_bounds__(256) void k_kgen(const float* __restrict__ Wf,
                                              short* __restrict__ Wb)
{
    __shared__ float md[cN * 6];
    int h = blockIdx.x, tid = threadIdx.x;
    for (int i = tid; i < cN * 6; i += 256)
        md[i] = Wf[WS_MODES + (size_t)h * cN * 6 + i];
    __syncthreads();
    int t0 = tid * 8;
    float acc[8] = {0.f, 0.f, 0.f, 0.f, 0.f, 0.f, 0.f, 0.f};
    for (int n = 0; n < cN; ++n) {
        float csr = md[n*6+0], csi = md[n*6+1];
        float zr  = md[n*6+2], zi  = md[n*6+3];
        float ar  = md[n*6+4], ai  = md[n*6+5];
        float mag = expf(ar * (float)t0);
        double ph = fmod((double)ai * (double)t0, 6.283185307179586);
        float s, c; sincosf((float)ph, &s, &c);
        float pr = mag * c, pi = mag * s;
#pragma unroll
        for (int i = 0; i < 8; ++i) {
            acc[i] += csr * pr - csi * pi;
            float tr = pr * zr - pi * zi;
            pi = pr * zi + pi * zr;
            pr = tr;
        }
    }
    short8 v;
#pragma unroll
    for (int i = 0; i < 8; ++i) v[i] = f2bf(2.f * acc[i]);
    *reinterpret_cast<short8*>(&Wb[S_A + (size_t)(BH + h) * 2048 + t0]) = v;
}

// ---------------- 256x256 8-phase GEMM core (BK=64, 512 thr, 8 waves) --------
// LDS ring: A half-slots (tb,half) at (tb*2+half)*8192 shorts; B at +32768.
// Phase schedule per tile t (quadrants Q00,Q01,Q11,Q10):
//   P0: rd A0,B0 ; stage (t+1,A1) ; MFMA Q00
//   P1: rd B1    ; stage (t+1,B0) ; MFMA Q01 (A0 held)
//   P2: rd A1    ; stage (t+2,A0) ; MFMA Q11 (B1 held)
//   P3: rd B0    ; stage (t+2,B1) ; vmcnt(4) ; MFMA Q10
// Swizzle: col ^= ((row>>2)&3)<<4 on global source + ds_read (linear LDS dest).
__device__ __forceinline__ void gemm8p_core(
    const short* __restrict__ Ag, int lda,
    const short* __restrict__ Bg, int ldb,
    int m0, int n0, int nt, short* lds, f32x4 (&acc)[4][4][2])
{
    const int tid  = threadIdx.x;
    const int wave = tid >> 6, lane = tid & 63;
    const int wm = wave >> 2, wn = wave & 3;
    const int lm = lane & 15, lk = lane >> 4;
    const int srow8 = lane >> 3;
    const int scol  = (lane & 7) * 8;

    auto stage = [&](const short* G, int ldg, int row0, int half, int kt, int sb) {
        short* l0 = lds + sb + (size_t)((kt & 1) * 2 + half) * 8192;
#pragma unroll
        for (int q = 0; q < 2; ++q) {
            int chunk = wave * 2 + q;
            int r = chunk * 8 + srow8;
            int c = scol ^ (((r >> 2) & 3) << 4);
            load_lds16(G + (size_t)(row0 + half * 128 + r) * ldg + kt * 64 + c,
                       l0 + chunk * 512);
        }
    };
    auto rdA = [&](int qa, int kt, int mi, int kk) -> short8 {
        int rl = wm * 64 + mi * 16 + lm;
        int c  = (kk * 32 + lk * 8) ^ (((rl >> 2) & 3) << 4);
        return *(const short8*)(lds + (size_t)((kt & 1) * 2 + qa) * 8192 + rl * 64 + c);
    };
    auto rdB = [&](int qb, int kt, int ni, int kk) -> short8 {
        int rl = wn * 32 + ni * 16 + lm;
        int c  = (kk * 32 + lk * 8) ^ (((rl >> 2) & 3) << 4);
        return *(const short8*)(lds + 32768 + (size_t)((kt & 1) * 2 + qb) * 8192 + rl * 64 + c);
    };

    // prologue: (0,A0),(0,B0),(0,B1),(0,A1),(1,A0),(1,B1)
    stage(Ag, lda, m0, 0, 0, 0);
    stage(Bg, ldb, n0, 0, 0, 32768);
    stage(Bg, ldb, n0, 1, 0, 32768);
    stage(Ag, lda, m0, 1, 0, 0);
    if (nt > 1) { stage(Ag, lda, m0, 0, 1, 0); stage(Bg, ldb, n0, 1, 1, 32768); }
    WAIT_VM(4);
    __builtin_amdgcn_s_barrier();

    short8 a[4][2], b[2][2];
    for (int t = 0; t < nt; ++t) {
        // ---- P0 ----
#pragma unroll
        for (int mi = 0; mi < 4; ++mi) { a[mi][0] = rdA(0, t, mi, 0); a[mi][1] = rdA(0, t, mi, 1); }
#pragma unroll
        for (int ni = 0; ni < 2; ++ni) { b[ni][0] = rdB(0, t, ni, 0); b[ni][1] = rdB(0, t, ni, 1); }
        if (t + 1 < nt) stage(Ag, lda, m0, 1, t + 1, 0);
        __builtin_amdgcn_s_barrier();
        WAIT_LGKM0();
        __builtin_amdgcn_s_setprio(1);
#pragma unroll
        for (int kk = 0; kk < 2; ++kk)
#pragma unroll
        for (int ni = 0; ni < 2; ++ni)
#pragma unroll
        for (int mi = 0; mi < 4; ++mi)
            acc[0][mi][ni] = __builtin_amdgcn_mfma_f32_16x16x32_bf16(a[mi][kk], b[ni][kk], acc[0][mi][ni], 0, 0, 0);
        __builtin_amdgcn_s_setprio(0);
        __builtin_amdgcn_s_barrier();
        // ---- P1 ----
#pragma unroll
        for (int ni = 0; ni < 2; ++ni) { b[ni][0] = rdB(1, t, ni, 0); b[ni][1] = rdB(1, t, ni, 1); }
        if (t + 1 < nt) stage(Bg, ldb, n0, 0, t + 1, 32768);
        __builtin_amdgcn_s_barrier();
        WAIT_LGKM0();
        __builtin_amdgcn_s_setprio(1);
#pragma unroll
        for (int kk = 0; kk < 2; ++kk)
#pragma unroll
        for (int ni = 0; ni < 2; ++ni)
#pragma unroll
        for (int mi = 0; mi < 4; ++mi)
            acc[1][mi][ni] = __builtin_amdgcn_mfma_f32_16x16x32_bf16(a[mi][kk], b[ni][kk], acc[1][mi][ni], 0, 0, 0);
        __builtin_amdgcn_s_setprio(0);
        __builtin_amdgcn_s_barrier();
        // ---- P2 ----
#pragma unroll
        for (int mi = 0; mi < 4; ++mi) { a[mi][0] = rdA(1, t, mi, 0); a[mi][1] = rdA(1, t, mi, 1); }
        if (t + 2 < nt) stage(Ag, lda, m0, 0, t + 2, 0);
        __builtin_amdgcn_s_barrier();
        WAIT_LGKM0();
        __builtin_amdgcn_s_setprio(1);
#pragma unroll
        for (int kk = 0; kk < 2; ++kk)
#pragma unroll
        for (int ni = 0; ni < 2; ++ni)
#pragma unroll
        for (int mi = 0; mi < 4; ++mi)
            acc[3][mi][ni] = __builtin_amdgcn_mfma_f32_16x16x32_bf16(a[mi][kk], b[ni][kk], acc[3][mi][ni], 0, 0, 0);
        __builtin_amdgcn_s_setprio(0);
        __builtin_amdgcn_s_barrier();
        // ---- P3 ----
#pragma unroll
        for (int ni = 0; ni < 2; ++ni) { b[ni][0] = rdB(0, t, ni, 0); b[ni][1] = rdB(0, t, ni, 1); }
        if (t + 2 < nt) stage(Bg, ldb, n0, 1, t + 2, 32768);
        if (t < nt - 2) { WAIT_VM(4); } else { WAIT_VM(0); }
        __builtin_amdgcn_s_barrier();
        WAIT_LGKM0();
        __builtin_amdgcn_s_setprio(1);
#pragma unroll
        for (int kk = 0; kk < 2; ++kk)
#pragma unroll
        for (int ni = 0; ni < 2; ++ni)
#pragma unroll
        for (int mi = 0; mi < 4; ++mi)
            acc[2][mi][ni] = __builtin_amdgcn_mfma_f32_16x16x32_bf16(a[mi][kk], b[ni][kk], acc[2][mi][ni], 0, 0, 0);
        __builtin_amdgcn_s_setprio(0);
        __builtin_amdgcn_s_barrier();
    }
}

// forward: U[0..4095][4096] = A_u x B1^T
__global__ __launch_bounds__(512, 2) void k_fwd8(short* __restrict__ Wb)
{
    __shared__ short lds_s[65536];
    int tile = (blockIdx.x & 7) * 32 + (blockIdx.x >> 3);
    const int m0 = (tile >> 4) * 256, n0 = (tile & 15) * 256;
    const int tid = threadIdx.x;
    const int wave = tid >> 6, lane = tid & 63;
    const int wm = wave >> 2, wn = wave & 3;
    const int lm = lane & 15, lk = lane >> 4;

    f32x4 acc[4][4][2] = {};
    gemm8p_core(Wb + S_A, 2048, Wb + S_B1, 2048, m0, n0, 32, lds_s, acc);

    short* U = Wb + S_U;
#pragma unroll
    for (int q = 0; q < 4; ++q)
#pragma unroll
    for (int mi = 0; mi < 4; ++mi)
#pragma unroll
    for (int ni = 0; ni < 2; ++ni)
#pragma unroll
    for (int r = 0; r < 4; ++r) {
        int row = m0 + (q >> 1) * 128 + wm * 64 + mi * 16 + lk * 4 + r;
        int col = n0 + (q & 1) * 128 + wn * 32 + ni * 16 + lm;
        U[(size_t)row * 4096 + col] = f2bf(acc[q][mi][ni][r]);
    }
}

// KF rows: U[4096+h][4096] = A_k x B1^T  (128^2 gload_lds kernel, 128 blocks)
__global__ __launch_bounds__(256, 2) void k_kfg(short* __restrict__ Wb)
{
    __shared__ __align__(16) short As[128][32];
    __shared__ __align__(16) short Bs[128][32];
    const short* A = Wb + S_A;
    const short* B = Wb + S_B1;
    short* U = Wb + S_U;
    const int tid = threadIdx.x;
    const int m0 = 4096 + blockIdx.y * 128, n0 = blockIdx.x * 128;
    const int wave = tid >> 6, lane = tid & 63;
    const int wr = wave >> 1, wc = wave & 1;
    const int lm = lane & 15, lk = lane >> 4;
    const int srow = lane >> 2, scol = (lane & 3) * 8;

    f32x4 acc[4][4] = {};
    for (int k0 = 0; k0 < 2048; k0 += 32) {
        __syncthreads();
        {
            int c0 = wave * 2;
            load_lds16(&A[(size_t)(m0 + c0*16      + srow)*2048 + k0 + scol], &As[c0*16][0]);
            load_lds16(&A[(size_t)(m0 + c0*16 + 16 + srow)*2048 + k0 + scol], &As[c0*16+16][0]);
            load_lds16(&B[(size_t)(n0 + c0*16      + srow)*2048 + k0 + scol], &Bs[c0*16][0]);
            load_lds16(&B[(size_t)(n0 + c0*16 + 16 + srow)*2048 + k0 + scol], &Bs[c0*16+16][0]);
        }
        __syncthreads();
        short8 a[4];
#pragma unroll
        for (int mi = 0; mi < 4; ++mi)
            a[mi] = *(const short8*)&As[wr*64 + mi*16 + lm][lk*8];
#pragma unroll
        for (int ni = 0; ni < 4; ++ni) {
            short8 b = *(const short8*)&Bs[wc*64 + ni*16 + lm][lk*8];
#pragma unroll
            for (int mi = 0; mi < 4; ++mi)
                acc[mi][ni] = __builtin_amdgcn_mfma_f32_16x16x32_bf16(a[mi], b, acc[mi][ni], 0, 0, 0);
        }
    }
#pragma unroll
    for (int mi = 0; mi < 4; ++mi)
#pragma unroll
    for (int ni = 0; ni < 4; ++ni)
#pragma unroll
    for (int r = 0; r < 4; ++r) {
        int row = m0 + wr*64 + mi*16 + lk*4 + r;
        int col = n0 + wc*64 + ni*16 + lm;
        U[(size_t)row * 4096 + col] = f2bf(acc[mi][ni][r]);
    }
}

// Ys[bh][j] / [2048+j] from U x KF, scale folded
__global__ __launch_bounds__(256) void k_mix(short* __restrict__ Wb)
{
    const short* U = Wb + S_U;
    short* Ys = Wb + S_YS;
    int bh = blockIdx.x;
    int h  = bh & (cH - 1);
    int j0 = threadIdx.x * 8;
    short8 c8  = *(const short8*)&U[(size_t)bh * 4096 + j0];
    short8 s8  = *(const short8*)&U[(size_t)bh * 4096 + 2048 + j0];
    short8 ck8 = *(const short8*)&U[(size_t)(BH + h) * 4096 + j0];
    short8 sk8 = *(const short8*)&U[(size_t)(BH + h) * 4096 + 2048 + j0];
    short8 yr, yi;
#pragma unroll
    for (int i = 0; i < 8; ++i) {
        float C  = bf2f(c8[i]),  S  = bf2f(s8[i]);
        float Ck = bf2f(ck8[i]), Sk = bf2f(sk8[i]);
        float sc = ((j0 + i) == 0 ? 1.0f : 2.0f) / (float)M2;
        yr[i] = f2bf(sc * (Ck * C - Sk * S));
        yi[i] = f2bf(sc * (Ck * S + Sk * C));
    }
    *(short8*)&Ys[(size_t)bh * 4096 + j0]        = yr;
    *(short8*)&Ys[(size_t)bh * 4096 + 2048 + j0] = yi;
}

// inverse: split-K=2, 8-phase. pass0 -> out (+skip), pass1 -> P1
__global__ __launch_bounds__(512, 2) void k_inv8(const float* __restrict__ u,
                                                 const float* __restrict__ Dp,
                                                 short* __restrict__ Wb,
                                                 float* __restrict__ out)
{
    __shared__ short lds_s[65536];
    int tile = (blockIdx.x & 7) * 32 + (blockIdx.x >> 3);
    const int pass = tile >> 7;
    const int rem  = tile & 127;
    const int m0 = (rem >> 3) * 256, n0 = (rem & 7) * 256;
    const int tid = threadIdx.x;
    const int wave = tid >> 6, lane = tid & 63;
    const int wm = wave >> 2, wn = wave & 3;
    const int lm = lane & 15, lk = lane >> 4;

    f32x4 acc[4][4][2] = {};
    const short* Ag = Wb + S_YS + pass * 2048;
    const short* Bg = Wb + S_T2 + pass * 2048;
    gemm8p_core(Ag, 4096, Bg, 4096, m0, n0, 32, lds_s, acc);

    // transpose epilogue
    float* P1 = (float*)(Wb + S_U);
    const int b  = m0 >> 9;
    const int h0 = m0 & 511;
    float (*T)[132] = (float(*)[132])lds_s;
    const int trow = tid >> 2;
    const int hs   = (tid & 3) * 32;
#pragma unroll
    for (int q = 0; q < 4; ++q) {
        __syncthreads();
#pragma unroll
        for (int mi = 0; mi < 4; ++mi)
#pragma unroll
        for (int ni = 0; ni < 2; ++ni) {
            int tl = wn * 32 + ni * 16 + lm;
            int hl = wm * 64 + mi * 16 + lk * 4;
            *(float4*)&T[tl][hl] = *(float4*)&acc[q][mi][ni];
        }
        __syncthreads();
        int tg = n0 + (q & 1) * 128 + trow;
        int hg = h0 + (q >> 1) * 128 + hs;
#pragma unroll
        for (int v = 0; v < 8; ++v) {
            size_t gidx = ((size_t)b * cL + tg) * cH + hg + v * 4;
            float4 yv = *(float4*)&T[trow][hs + v * 4];
            if (pass == 0) {
                float4 uv = *(const float4*)&u[gidx];
                float4 dv = *(const float4*)&Dp[hg + v * 4];
                yv.x += dv.x * uv.x;
                yv.y += dv.y * uv.y;
                yv.z += dv.z * uv.z;
                yv.w += dv.w * uv.w;
                *(float4*)&out[gidx] = yv;
            } else {
                *(float4*)&P1[gidx] = yv;
            }
        }
    }
}

// out += P1  (out: 8,388,608 floats = 2,097,152 float4; 524,288 threads x 4)
__global__ __launch_bounds__(256) void k_comb(float* __restrict__ out,
                                              const float* __restrict__ P1)
{
    int i = blockIdx.x * 256 + threadIdx.x;
#pragma unroll
    for (int v = 0; v < 4; ++v) {
        size_t idx = ((size_t)v * 524288 + i) * 4;
        float4 a = *(float4*)&out[idx];
        float4 p = *(const float4*)&P1[idx];
        a.x += p.x; a.y += p.y; a.z += p.z; a.w += p.w;
        *(float4*)&out[idx] = a;
    }
}

extern "C" void kernel_launch(void* const* d_in, const int* in_sizes, int n_in,
                              void* d_out, int out_size, void* d_ws, size_t ws_size,
                              hipStream_t stream) {
    const float* u    = (const float*)d_in[0];
    const float* w_re = (const float*)d_in[1];
    const float* w_im = (const float*)d_in[2];
    const float* C_re = (const float*)d_in[3];
    const float* C_im = (const float*)d_in[4];
    const float* Dp   = (const float*)d_in[5];
    const float* dt   = (const float*)d_in[6];
    float* out = (float*)d_out;
    float* Wf  = (float*)d_ws;
    short* Wb  = (short*)d_ws;

    hipLaunchKernelGGL(k_precomp, dim3((cH * cN + 255) / 256), dim3(256), 0, stream,
                       w_re, w_im, C_re, C_im, dt, Wf);
    hipLaunchKernelGGL(k_tab1,  dim3((2048 * 2048) / 256), dim3(256), 0, stream, Wb);
    hipLaunchKernelGGL(k_tab2,  dim3((2048 * 2048) / 256), dim3(256), 0, stream, Wb);
    hipLaunchKernelGGL(k_trans, dim3(cL / 64, cH / 64, cB), dim3(256), 0, stream, u, Wb);
    hipLaunchKernelGGL(k_kgen,  dim3(cH), dim3(256), 0, stream, Wf, Wb);
    hipLaunchKernelGGL(k_fwd8,  dim3(256), dim3(512), 0, stream, Wb);
    hipLaunchKernelGGL(k_kfg,   dim3(32, 4), dim3(256), 0, stream, Wb);
    hipLaunchKernelGGL(k_mix,   dim3(BH), dim3(256), 0, stream, Wb);
    hipLaunchKernelGGL(k_inv8,  dim3(256), dim3(512), 0, stream, u, Dp, Wb, out);
    hipLaunchKernelGGL(k_comb,  dim3(2048), dim3(256), 0, stream, out, (const float*)(Wb + S_U));
}

// Round 7
// 257.483 us; speedup vs baseline: 1.2071x; 1.2071x over previous
//
#include <hip/hip_runtime.h>
#include <hip/hip_bf16.h>
#include <math.h>

// S4DConv via MFMA: B=8, L=2048, H=512, N=64, CH=1
//   A u-rows [4096][2048], k-rows [512][2048]  (bf16)
//   U[4608][4096] = A x B1^T : u-rows via 256^2 8-phase GEMM (k_fwd8),
//                              k-rows via small 128^2 GEMM (k_kfg)
//   Ys = scale * (KF * U) complex -> bf16                            [k_mix]
//   y[bh][t] = Ys x T2^T, K=4096 split-K=2, 8-phase (k_inv8) + combine

namespace {
constexpr int cB = 8;
constexpr int cL = 2048;
constexpr int cH = 512;
constexpr int cN = 64;
constexpr int M1 = 4095;
constexpr int M2 = 4096;
constexpr int BH = cB * cH;            // 4096
constexpr int MA = BH + cH;            // 4608

// float region
constexpr size_t WS_MODES = 0;                        // [H][N][6]
// short regions
constexpr size_t S0   = 2 * ((size_t)cH * cN * 6);
constexpr size_t S_B1 = S0;                           // [4096][2048]
constexpr size_t S_A  = S_B1 + (size_t)4096 * 2048;   // [4608][2048]
constexpr size_t S_T2 = S_A  + (size_t)MA * 2048;     // [2048][4096]
constexpr size_t S_U  = S_T2 + (size_t)2048 * 4096;   // [4608][4096]; P1 (fp32 [4096][2048]) overlays after k_mix
constexpr size_t S_YS = S0;                           // overlay [4096][4096]
}

typedef __attribute__((ext_vector_type(8))) short short8;
typedef __attribute__((ext_vector_type(4))) float f32x4;

static __device__ inline short f2bf(float x) {
    __hip_bfloat16 h = __float2bfloat16(x);
    return *reinterpret_cast<short*>(&h);
}
static __device__ inline float bf2f(short s) {
    return __uint_as_float(((unsigned int)(unsigned short)s) << 16);
}
static __device__ __forceinline__ void load_lds16(const short* g, short* l) {
    __builtin_amdgcn_global_load_lds(
        (const __attribute__((address_space(1))) void*)g,
        (__attribute__((address_space(3))) void*)l, 16, 0, 0);
}
#define WAIT_LGKM0() do { asm volatile("s_waitcnt lgkmcnt(0)" ::: "memory"); \
                          __builtin_amdgcn_sched_barrier(0); } while (0)
#define WAIT_VM(n)   do { asm volatile("s_waitcnt vmcnt(" #n ")" ::: "memory"); \
                          __builtin_amdgcn_sched_barrier(0); } while (0)

__global__ __launch_bounds__(256) void k_precomp(
    const float* __restrict__ w_re, const float* __restrict__ w_im,
    const float* __restrict__ C_re, const float* __restrict__ C_im,
    const float* __restrict__ dt, float* __restrict__ W)
{
    int idx = blockIdx.x * 256 + threadIdx.x;
    if (idx >= cH * cN) return;
    int h = idx / cN;
    double dtv = dt[h];
    double wr = w_re[idx], wi = w_im[idx];
    double ar = wr * dtv, ai = wi * dtv;
    double er = exp(ar);
    double zs, zc; sincos(ai, &zs, &zc);
    double zr = er * zc, zi = er * zs;
    double nr = zr - 1.0, ni = zi;
    double inv = 1.0 / (wr * wr + wi * wi);
    double gr = (nr * wr + ni * wi) * inv;
    double gi = (ni * wr - nr * wi) * inv;
    double cr = C_re[idx], ci = C_im[idx];
    double csr = cr * gr - ci * gi, csi = cr * gi + ci * gr;
    float* m = W + WS_MODES + (size_t)idx * 6;
    m[0] = (float)csr; m[1] = (float)csi;
    m[2] = (float)zr;  m[3] = (float)zi;
    m[4] = (float)ar;  m[5] = (float)ai;
}

__global__ __launch_bounds__(256) void k_tab1(short* __restrict__ Wb)
{
    int g = blockIdx.x * 256 + threadIdx.x;
    int j = g >> 11, t = g & 2047;
    int p = (j * t) % M1;
    float s, c;
    sincosf((6.283185307179586f / (float)M1) * (float)p, &s, &c);
    Wb[S_B1 + (size_t)j * 2048 + t]          = f2bf(c);
    Wb[S_B1 + (size_t)(2048 + j) * 2048 + t] = f2bf(s);
}

__global__ __launch_bounds__(256) void k_tab2(short* __restrict__ Wb)
{
    int g = blockIdx.x * 256 + threadIdx.x;
    int t = g >> 11, j = g & 2047;
    int p = (t * j) & (M2 - 1);
    float s, c;
    sincosf((6.283185307179586f / (float)M2) * (float)p, &s, &c);
    Wb[S_T2 + (size_t)t * 4096 + j]        = f2bf(c);
    Wb[S_T2 + (size_t)t * 4096 + 2048 + j] = f2bf(s);
}

__global__ __launch_bounds__(256) void k_trans(const float* __restrict__ u,
                                               short* __restrict__ Wb)
{
    __shared__ float tile[64][65];
    int t0 = blockIdx.x * 64;
    int h0 = blockIdx.y * 64;
    int b  = blockIdx.z;
    int cx = threadIdx.x & 63, r0 = threadIdx.x >> 6;
#pragma unroll
    for (int i = 0; i < 16; ++i) {
        int row = r0 + i * 4;
        tile[row][cx] = u[((size_t)b * cL + t0 + row) * cH + h0 + cx];
    }
    __syncthreads();
    short* A = Wb + S_A;
#pragma unroll
    for (int i = 0; i < 16; ++i) {
        int hrow = r0 + i * 4;
        A[(size_t)(b * cH + h0 + hrow) * 2048 + t0 + cx] = f2bf(tile[cx][hrow]);
    }
}

__global__ __launch_bounds__(256) void k_kgen(const float* __restrict__ Wf,
                                              short* __restrict__ Wb)
{
    __shared__ float md[cN * 6];
    int h = blockIdx.x, tid = threadIdx.x;
    for (int i = tid; i < cN * 6; i += 256)
        md[i] = Wf[WS_MODES + (size_t)h * cN * 6 + i];
    __syncthreads();
    int t0 = tid * 8;
    float acc[8] = {0.f, 0.f, 0.f, 0.f, 0.f, 0.f, 0.f, 0.f};
    for (int n = 0; n < cN; ++n) {
        float csr = md[n*6+0], csi = md[n*6+1];
        float zr  = md[n*6+2], zi  = md[n*6+3];
        float ar  = md[n*6+4], ai  = md[n*6+5];
        float mag = expf(ar * (float)t0);
        double ph = fmod((double)ai * (double)t0, 6.283185307179586);
        float s, c; sincosf((float)ph, &s, &c);
        float pr = mag * c, pi = mag * s;
#pragma unroll
        for (int i = 0; i < 8; ++i) {
            acc[i] += csr * pr - csi * pi;
            float tr = pr * zr - pi * zi;
            pi = pr * zi + pi * zr;
            pr = tr;
        }
    }
    short8 v;
#pragma unroll
    for (int i = 0; i < 8; ++i) v[i] = f2bf(2.f * acc[i]);
    *reinterpret_cast<short8*>(&Wb[S_A + (size_t)(BH + h) * 2048 + t0]) = v;
}

// ---------------- 256x256 8-phase GEMM core (BK=64, 512 thr, 8 waves) --------
// LDS ring: A half-slots (tb,half) at (tb*2+half)*8192 shorts; B at +32768.
// Phase schedule per tile t (quadrants Q00,Q01,Q11,Q10):
//   P0: rd A0,B0 ; stage (t+1,A1) ; MFMA Q00
//   P1: rd B1    ; stage (t+1,B0) ; MFMA Q01 (A0 held)
//   P2: rd A1    ; stage (t+2,A0) ; MFMA Q11 (B1 held)
//   P3: rd B0    ; stage (t+2,B1) ; vmcnt(4) ; MFMA Q10
// Swizzle (G4): col_shorts ^= (row&7)<<3  == byte ^= (row&7)<<4
//   -> 8 distinct 16B slots per 8 rows: 2 lanes/bank = conflict-free.
//   Applied to BOTH global stage source and ds_read (rule #21).
__device__ __forceinline__ void gemm8p_core(
    const short* __restrict__ Ag, int lda,
    const short* __restrict__ Bg, int ldb,
    int m0, int n0, int nt, short* lds, f32x4 (&acc)[4][4][2])
{
    const int tid  = threadIdx.x;
    const int wave = tid >> 6, lane = tid & 63;
    const int wm = wave >> 2, wn = wave & 3;
    const int lm = lane & 15, lk = lane >> 4;
    const int srow8 = lane >> 3;
    const int scol  = (lane & 7) * 8;

    auto stage = [&](const short* G, int ldg, int row0, int half, int kt, int sb) {
        short* l0 = lds + sb + (size_t)((kt & 1) * 2 + half) * 8192;
#pragma unroll
        for (int q = 0; q < 2; ++q) {
            int chunk = wave * 2 + q;
            int r = chunk * 8 + srow8;
            int c = scol ^ ((r & 7) << 3);
            load_lds16(G + (size_t)(row0 + half * 128 + r) * ldg + kt * 64 + c,
                       l0 + chunk * 512);
        }
    };
    auto rdA = [&](int qa, int kt, int mi, int kk) -> short8 {
        int rl = wm * 64 + mi * 16 + lm;
        int c  = (kk * 32 + lk * 8) ^ ((rl & 7) << 3);
        return *(const short8*)(lds + (size_t)((kt & 1) * 2 + qa) * 8192 + rl * 64 + c);
    };
    auto rdB = [&](int qb, int kt, int ni, int kk) -> short8 {
        int rl = wn * 32 + ni * 16 + lm;
        int c  = (kk * 32 + lk * 8) ^ ((rl & 7) << 3);
        return *(const short8*)(lds + 32768 + (size_t)((kt & 1) * 2 + qb) * 8192 + rl * 64 + c);
    };

    // prologue: (0,A0),(0,B0),(0,B1),(0,A1),(1,A0),(1,B1)
    stage(Ag, lda, m0, 0, 0, 0);
    stage(Bg, ldb, n0, 0, 0, 32768);
    stage(Bg, ldb, n0, 1, 0, 32768);
    stage(Ag, lda, m0, 1, 0, 0);
    if (nt > 1) { stage(Ag, lda, m0, 0, 1, 0); stage(Bg, ldb, n0, 1, 1, 32768); }
    WAIT_VM(4);
    __builtin_amdgcn_s_barrier();

    short8 a[4][2], b[2][2];
    for (int t = 0; t < nt; ++t) {
        // ---- P0 ----
#pragma unroll
        for (int mi = 0; mi < 4; ++mi) { a[mi][0] = rdA(0, t, mi, 0); a[mi][1] = rdA(0, t, mi, 1); }
#pragma unroll
        for (int ni = 0; ni < 2; ++ni) { b[ni][0] = rdB(0, t, ni, 0); b[ni][1] = rdB(0, t, ni, 1); }
        if (t + 1 < nt) stage(Ag, lda, m0, 1, t + 1, 0);
        __builtin_amdgcn_s_barrier();
        WAIT_LGKM0();
        __builtin_amdgcn_s_setprio(1);
#pragma unroll
        for (int kk = 0; kk < 2; ++kk)
#pragma unroll
        for (int ni = 0; ni < 2; ++ni)
#pragma unroll
        for (int mi = 0; mi < 4; ++mi)
            acc[0][mi][ni] = __builtin_amdgcn_mfma_f32_16x16x32_bf16(a[mi][kk], b[ni][kk], acc[0][mi][ni], 0, 0, 0);
        __builtin_amdgcn_s_setprio(0);
        __builtin_amdgcn_s_barrier();
        // ---- P1 ----
#pragma unroll
        for (int ni = 0; ni < 2; ++ni) { b[ni][0] = rdB(1, t, ni, 0); b[ni][1] = rdB(1, t, ni, 1); }
        if (t + 1 < nt) stage(Bg, ldb, n0, 0, t + 1, 32768);
        __builtin_amdgcn_s_barrier();
        WAIT_LGKM0();
        __builtin_amdgcn_s_setprio(1);
#pragma unroll
        for (int kk = 0; kk < 2; ++kk)
#pragma unroll
        for (int ni = 0; ni < 2; ++ni)
#pragma unroll
        for (int mi = 0; mi < 4; ++mi)
            acc[1][mi][ni] = __builtin_amdgcn_mfma_f32_16x16x32_bf16(a[mi][kk], b[ni][kk], acc[1][mi][ni], 0, 0, 0);
        __builtin_amdgcn_s_setprio(0);
        __builtin_amdgcn_s_barrier();
        // ---- P2 ----
#pragma unroll
        for (int mi = 0; mi < 4; ++mi) { a[mi][0] = rdA(1, t, mi, 0); a[mi][1] = rdA(1, t, mi, 1); }
        if (t + 2 < nt) stage(Ag, lda, m0, 0, t + 2, 0);
        __builtin_amdgcn_s_barrier();
        WAIT_LGKM0();
        __builtin_amdgcn_s_setprio(1);
#pragma unroll
        for (int kk = 0; kk < 2; ++kk)
#pragma unroll
        for (int ni = 0; ni < 2; ++ni)
#pragma unroll
        for (int mi = 0; mi < 4; ++mi)
            acc[3][mi][ni] = __builtin_amdgcn_mfma_f32_16x16x32_bf16(a[mi][kk], b[ni][kk], acc[3][mi][ni], 0, 0, 0);
        __builtin_amdgcn_s_setprio(0);
        __builtin_amdgcn_s_barrier();
        // ---- P3 ----
#pragma unroll
        for (int ni = 0; ni < 2; ++ni) { b[ni][0] = rdB(0, t, ni, 0); b[ni][1] = rdB(0, t, ni, 1); }
        if (t + 2 < nt) stage(Bg, ldb, n0, 1, t + 2, 32768);
        if (t < nt - 2) { WAIT_VM(4); } else { WAIT_VM(0); }
        __builtin_amdgcn_s_barrier();
        WAIT_LGKM0();
        __builtin_amdgcn_s_setprio(1);
#pragma unroll
        for (int kk = 0; kk < 2; ++kk)
#pragma unroll
        for (int ni = 0; ni < 2; ++ni)
#pragma unroll
        for (int mi = 0; mi < 4; ++mi)
            acc[2][mi][ni] = __builtin_amdgcn_mfma_f32_16x16x32_bf16(a[mi][kk], b[ni][kk], acc[2][mi][ni], 0, 0, 0);
        __builtin_amdgcn_s_setprio(0);
        __builtin_amdgcn_s_barrier();
    }
}

// forward: U[0..4095][4096] = A_u x B1^T
__global__ __launch_bounds__(512, 2) void k_fwd8(short* __restrict__ Wb)
{
    __shared__ short lds_s[65536];
    int tile = (blockIdx.x & 7) * 32 + (blockIdx.x >> 3);
    const int m0 = (tile >> 4) * 256, n0 = (tile & 15) * 256;
    const int tid = threadIdx.x;
    const int wave = tid >> 6, lane = tid & 63;
    const int wm = wave >> 2, wn = wave & 3;
    const int lm = lane & 15, lk = lane >> 4;

    f32x4 acc[4][4][2] = {};
    gemm8p_core(Wb + S_A, 2048, Wb + S_B1, 2048, m0, n0, 32, lds_s, acc);

    short* U = Wb + S_U;
#pragma unroll
    for (int q = 0; q < 4; ++q)
#pragma unroll
    for (int mi = 0; mi < 4; ++mi)
#pragma unroll
    for (int ni = 0; ni < 2; ++ni)
#pragma unroll
    for (int r = 0; r < 4; ++r) {
        int row = m0 + (q >> 1) * 128 + wm * 64 + mi * 16 + lk * 4 + r;
        int col = n0 + (q & 1) * 128 + wn * 32 + ni * 16 + lm;
        U[(size_t)row * 4096 + col] = f2bf(acc[q][mi][ni][r]);
    }
}

// KF rows: U[4096+h][4096] = A_k x B1^T  (128^2 gload_lds kernel, 128 blocks)
__global__ __launch_bounds__(256, 2) void k_kfg(short* __restrict__ Wb)
{
    __shared__ __align__(16) short As[128][32];
    __shared__ __align__(16) short Bs[128][32];
    const short* A = Wb + S_A;
    const short* B = Wb + S_B1;
    short* U = Wb + S_U;
    const int tid = threadIdx.x;
    const int m0 = 4096 + blockIdx.y * 128, n0 = blockIdx.x * 128;
    const int wave = tid >> 6, lane = tid & 63;
    const int wr = wave >> 1, wc = wave & 1;
    const int lm = lane & 15, lk = lane >> 4;
    const int srow = lane >> 2, scol = (lane & 3) * 8;

    f32x4 acc[4][4] = {};
    for (int k0 = 0; k0 < 2048; k0 += 32) {
        __syncthreads();
        {
            int c0 = wave * 2;
            load_lds16(&A[(size_t)(m0 + c0*16      + srow)*2048 + k0 + scol], &As[c0*16][0]);
            load_lds16(&A[(size_t)(m0 + c0*16 + 16 + srow)*2048 + k0 + scol], &As[c0*16+16][0]);
            load_lds16(&B[(size_t)(n0 + c0*16      + srow)*2048 + k0 + scol], &Bs[c0*16][0]);
            load_lds16(&B[(size_t)(n0 + c0*16 + 16 + srow)*2048 + k0 + scol], &Bs[c0*16+16][0]);
        }
        __syncthreads();
        short8 a[4];
#pragma unroll
        for (int mi = 0; mi < 4; ++mi)
            a[mi] = *(const short8*)&As[wr*64 + mi*16 + lm][lk*8];
#pragma unroll
        for (int ni = 0; ni < 4; ++ni) {
            short8 b = *(const short8*)&Bs[wc*64 + ni*16 + lm][lk*8];
#pragma unroll
            for (int mi = 0; mi < 4; ++mi)
                acc[mi][ni] = __builtin_amdgcn_mfma_f32_16x16x32_bf16(a[mi], b, acc[mi][ni], 0, 0, 0);
        }
    }
#pragma unroll
    for (int mi = 0; mi < 4; ++mi)
#pragma unroll
    for (int ni = 0; ni < 4; ++ni)
#pragma unroll
    for (int r = 0; r < 4; ++r) {
        int row = m0 + wr*64 + mi*16 + lk*4 + r;
        int col = n0 + wc*64 + ni*16 + lm;
        U[(size_t)row * 4096 + col] = f2bf(acc[mi][ni][r]);
    }
}

// Ys[bh][j] / [2048+j] from U x KF, scale folded
__global__ __launch_bounds__(256) void k_mix(short* __restrict__ Wb)
{
    const short* U = Wb + S_U;
    short* Ys = Wb + S_YS;
    int bh = blockIdx.x;
    int h  = bh & (cH - 1);
    int j0 = threadIdx.x * 8;
    short8 c8  = *(const short8*)&U[(size_t)bh * 4096 + j0];
    short8 s8  = *(const short8*)&U[(size_t)bh * 4096 + 2048 + j0];
    short8 ck8 = *(const short8*)&U[(size_t)(BH + h) * 4096 + j0];
    short8 sk8 = *(const short8*)&U[(size_t)(BH + h) * 4096 + 2048 + j0];
    short8 yr, yi;
#pragma unroll
    for (int i = 0; i < 8; ++i) {
        float C  = bf2f(c8[i]),  S  = bf2f(s8[i]);
        float Ck = bf2f(ck8[i]), Sk = bf2f(sk8[i]);
        float sc = ((j0 + i) == 0 ? 1.0f : 2.0f) / (float)M2;
        yr[i] = f2bf(sc * (Ck * C - Sk * S));
        yi[i] = f2bf(sc * (Ck * S + Sk * C));
    }
    *(short8*)&Ys[(size_t)bh * 4096 + j0]        = yr;
    *(short8*)&Ys[(size_t)bh * 4096 + 2048 + j0] = yi;
}

// inverse: split-K=2, 8-phase. pass0 -> out (+skip), pass1 -> P1
__global__ __launch_bounds__(512, 2) void k_inv8(const float* __restrict__ u,
                                                 const float* __restrict__ Dp,
                                                 short* __restrict__ Wb,
                                                 float* __restrict__ out)
{
    __shared__ short lds_s[65536];
    int tile = (blockIdx.x & 7) * 32 + (blockIdx.x >> 3);
    const int pass = tile >> 7;
    const int rem  = tile & 127;
    const int m0 = (rem >> 3) * 256, n0 = (rem & 7) * 256;
    const int tid = threadIdx.x;
    const int wave = tid >> 6, lane = tid & 63;
    const int wm = wave >> 2, wn = wave & 3;
    const int lm = lane & 15, lk = lane >> 4;

    f32x4 acc[4][4][2] = {};
    const short* Ag = Wb + S_YS + pass * 2048;
    const short* Bg = Wb + S_T2 + pass * 2048;
    gemm8p_core(Ag, 4096, Bg, 4096, m0, n0, 32, lds_s, acc);

    // transpose epilogue; store pattern: lanes 0-31 cover one full t-row's
    // 128 floats (512B contiguous), lanes 32-63 the next row -> coalesced.
    float* P1 = (float*)(Wb + S_U);
    const int b  = m0 >> 9;
    const int h0 = m0 & 511;
    float (*T)[132] = (float(*)[132])lds_s;
    const int trow2 = tid >> 5;          // 0..15
    const int hch   = (tid & 31) * 4;    // 0..124
#pragma unroll
    for (int q = 0; q < 4; ++q) {
        __syncthreads();
#pragma unroll
        for (int mi = 0; mi < 4; ++mi)
#pragma unroll
        for (int ni = 0; ni < 2; ++ni) {
            int tl = wn * 32 + ni * 16 + lm;
            int hl = wm * 64 + mi * 16 + lk * 4;
            *(float4*)&T[tl][hl] = *(float4*)&acc[q][mi][ni];
        }
        __syncthreads();
        int hg = h0 + (q >> 1) * 128 + hch;
        float4 dv = *(const float4*)&Dp[hg];
#pragma unroll
        for (int it = 0; it < 8; ++it) {
            int tl = trow2 + it * 16;
            int tg = n0 + (q & 1) * 128 + tl;
            size_t gidx = ((size_t)b * cL + tg) * cH + hg;
            float4 yv = *(float4*)&T[tl][hch];
            if (pass == 0) {
                float4 uv = *(const float4*)&u[gidx];
                yv.x += dv.x * uv.x;
                yv.y += dv.y * uv.y;
                yv.z += dv.z * uv.z;
                yv.w += dv.w * uv.w;
                *(float4*)&out[gidx] = yv;
            } else {
                *(float4*)&P1[gidx] = yv;
            }
        }
    }
}

// out += P1  (out: 8,388,608 floats = 2,097,152 float4; 524,288 threads x 4)
__global__ __launch_bounds__(256) void k_comb(float* __restrict__ out,
                                              const float* __restrict__ P1)
{
    int i = blockIdx.x * 256 + threadIdx.x;
#pragma unroll
    for (int v = 0; v < 4; ++v) {
        size_t idx = ((size_t)v * 524288 + i) * 4;
        float4 a = *(float4*)&out[idx];
        float4 p = *(const float4*)&P1[idx];
        a.x += p.x; a.y += p.y; a.z += p.z; a.w += p.w;
        *(float4*)&out[idx] = a;
    }
}

extern "C" void kernel_launch(void* const* d_in, const int* in_sizes, int n_in,
                              void* d_out, int out_size, void* d_ws, size_t ws_size,
                              hipStream_t stream) {
    const float* u    = (const float*)d_in[0];
    const float* w_re = (const float*)d_in[1];
    const float* w_im = (const float*)d_in[2];
    const float* C_re = (const float*)d_in[3];
    const float* C_im = (const float*)d_in[4];
    const float* Dp   = (const float*)d_in[5];
    const float* dt   = (const float*)d_in[6];
    float* out = (float*)d_out;
    float* Wf  = (float*)d_ws;
    short* Wb  = (short*)d_ws;

    hipLaunchKernelGGL(k_precomp, dim3((cH * cN + 255) / 256), dim3(256), 0, stream,
                       w_re, w_im, C_re, C_im, dt, Wf);
    hipLaunchKernelGGL(k_tab1,  dim3((2048 * 2048) / 256), dim3(256), 0, stream, Wb);
    hipLaunchKernelGGL(k_tab2,  dim3((2048 * 2048) / 256), dim3(256), 0, stream, Wb);
    hipLaunchKernelGGL(k_trans, dim3(cL / 64, cH / 64, cB), dim3(256), 0, stream, u, Wb);
    hipLaunchKernelGGL(k_kgen,  dim3(cH), dim3(256), 0, stream, Wf, Wb);
    hipLaunchKernelGGL(k_fwd8,  dim3(256), dim3(512), 0, stream, Wb);
    hipLaunchKernelGGL(k_kfg,   dim3(32, 4), dim3(256), 0, stream, Wb);
    hipLaunchKernelGGL(k_mix,   dim3(BH), dim3(256), 0, stream, Wb);
    hipLaunchKernelGGL(k_inv8,  dim3(256), dim3(512), 0, stream, u, Dp, Wb, out);
    hipLaunchKernelGGL(k_comb,  dim3(2048), dim3(256), 0, stream, out, (const float*)(Wb + S_U));
}

// Round 8
// 250.099 us; speedup vs baseline: 1.2427x; 1.0295x over previous
//
#include <hip/hip_runtime.h>
#include <hip/hip_bf16.h>
#include <math.h>

// S4DConv via MFMA: B=8, L=2048, H=512, N=64, CH=1
//   A u-rows [4096][2048], k-rows [512][2048]  (bf16)
//   B1' interleaved: row 2j = cos(2pi jt/4095), row 2j+1 = sin
//   KF rows: U[4096+h] = A_k x B1'^T (k_kfg, runs FIRST)
//   k_fwd8: U = A_u x B1'^T, epilogue fuses complex mix -> Ys (in U region)
//   k_inv8: y = Ys x T2^T, K=4096 split-K=2 + k_comb (P1 in dead B1 region)

namespace {
constexpr int cB = 8;
constexpr int cL = 2048;
constexpr int cH = 512;
constexpr int cN = 64;
constexpr int M1 = 4095;
constexpr int M2 = 4096;
constexpr int BH = cB * cH;            // 4096
constexpr int MA = BH + cH;            // 4608

// float region
constexpr size_t WS_MODES = 0;                        // [H][N][6]
// short regions
constexpr size_t S0   = 2 * ((size_t)cH * cN * 6);
constexpr size_t S_B1 = S0;                           // [4096][2048] interleaved; P1 fp32 overlay after fwd
constexpr size_t S_A  = S_B1 + (size_t)4096 * 2048;   // [4608][2048]
constexpr size_t S_T2 = S_A  + (size_t)MA * 2048;     // [2048][4096]
constexpr size_t S_U  = S_T2 + (size_t)2048 * 4096;   // [4608][4096]: rows<4096 become Ys; rows 4096+ = KF
}

typedef __attribute__((ext_vector_type(8))) short short8;
typedef __attribute__((ext_vector_type(4))) short sh4;
typedef __attribute__((ext_vector_type(4))) float f32x4;

static __device__ inline short f2bf(float x) {
    __hip_bfloat16 h = __float2bfloat16(x);
    return *reinterpret_cast<short*>(&h);
}
static __device__ inline float bf2f(short s) {
    return __uint_as_float(((unsigned int)(unsigned short)s) << 16);
}
static __device__ __forceinline__ void load_lds16(const short* g, short* l) {
    __builtin_amdgcn_global_load_lds(
        (const __attribute__((address_space(1))) void*)g,
        (__attribute__((address_space(3))) void*)l, 16, 0, 0);
}
#define WAIT_LGKM0() do { asm volatile("s_waitcnt lgkmcnt(0)" ::: "memory"); \
                          __builtin_amdgcn_sched_barrier(0); } while (0)
#define WAIT_VM(n)   do { asm volatile("s_waitcnt vmcnt(" #n ")" ::: "memory"); \
                          __builtin_amdgcn_sched_barrier(0); } while (0)

__global__ __launch_bounds__(256) void k_precomp(
    const float* __restrict__ w_re, const float* __restrict__ w_im,
    const float* __restrict__ C_re, const float* __restrict__ C_im,
    const float* __restrict__ dt, float* __restrict__ W)
{
    int idx = blockIdx.x * 256 + threadIdx.x;
    if (idx >= cH * cN) return;
    int h = idx / cN;
    double dtv = dt[h];
    double wr = w_re[idx], wi = w_im[idx];
    double ar = wr * dtv, ai = wi * dtv;
    double er = exp(ar);
    double zs, zc; sincos(ai, &zs, &zc);
    double zr = er * zc, zi = er * zs;
    double nr = zr - 1.0, ni = zi;
    double inv = 1.0 / (wr * wr + wi * wi);
    double gr = (nr * wr + ni * wi) * inv;
    double gi = (ni * wr - nr * wi) * inv;
    double cr = C_re[idx], ci = C_im[idx];
    double csr = cr * gr - ci * gi, csi = cr * gi + ci * gr;
    float* m = W + WS_MODES + (size_t)idx * 6;
    m[0] = (float)csr; m[1] = (float)csi;
    m[2] = (float)zr;  m[3] = (float)zi;
    m[4] = (float)ar;  m[5] = (float)ai;
}

// B1'[2j][t]=cos(2pi jt/4095), B1'[2j+1][t]=sin; vectorized: thread owns 8 t
__global__ __launch_bounds__(256) void k_tab1(short* __restrict__ Wb)
{
    int j  = blockIdx.x;            // 0..2047
    int t0 = threadIdx.x * 8;
    int p  = (int)(((long)j * t0) % M1);
    short8 vc, vs;
#pragma unroll
    for (int i = 0; i < 8; ++i) {
        float s, c;
        sincosf((6.283185307179586f / (float)M1) * (float)p, &s, &c);
        vc[i] = f2bf(c); vs[i] = f2bf(s);
        p += j; if (p >= M1) p -= M1;
    }
    *(short8*)&Wb[S_B1 + (size_t)(2 * j)     * 2048 + t0] = vc;
    *(short8*)&Wb[S_B1 + (size_t)(2 * j + 1) * 2048 + t0] = vs;
}

// T2[t][j]=cos(2pi tj/4096), T2[t][2048+j]=sin; thread owns 8 j
__global__ __launch_bounds__(256) void k_tab2(short* __restrict__ Wb)
{
    int t  = blockIdx.x;            // 0..2047
    int j0 = threadIdx.x * 8;
    int p  = (t * j0) & (M2 - 1);
    short8 vc, vs;
#pragma unroll
    for (int i = 0; i < 8; ++i) {
        float s, c;
        sincosf((6.283185307179586f / (float)M2) * (float)p, &s, &c);
        vc[i] = f2bf(c); vs[i] = f2bf(s);
        p = (p + t) & (M2 - 1);
    }
    *(short8*)&Wb[S_T2 + (size_t)t * 4096 + j0]        = vc;
    *(short8*)&Wb[S_T2 + (size_t)t * 4096 + 2048 + j0] = vs;
}

__global__ __launch_bounds__(256) void k_trans(const float* __restrict__ u,
                                               short* __restrict__ Wb)
{
    __shared__ float tile[64][65];
    int t0 = blockIdx.x * 64;
    int h0 = blockIdx.y * 64;
    int b  = blockIdx.z;
    int cx = threadIdx.x & 63, r0 = threadIdx.x >> 6;
#pragma unroll
    for (int i = 0; i < 16; ++i) {
        int row = r0 + i * 4;
        tile[row][cx] = u[((size_t)b * cL + t0 + row) * cH + h0 + cx];
    }
    __syncthreads();
    short* A = Wb + S_A;
#pragma unroll
    for (int i = 0; i < 16; ++i) {
        int hrow = r0 + i * 4;
        A[(size_t)(b * cH + h0 + hrow) * 2048 + t0 + cx] = f2bf(tile[cx][hrow]);
    }
}

__global__ __launch_bounds__(256) void k_kgen(const float* __restrict__ Wf,
                                              short* __restrict__ Wb)
{
    __shared__ float md[cN * 6];
    int h = blockIdx.x, tid = threadIdx.x;
    for (int i = tid; i < cN * 6; i += 256)
        md[i] = Wf[WS_MODES + (size_t)h * cN * 6 + i];
    __syncthreads();
    int t0 = tid * 8;
    float acc[8] = {0.f, 0.f, 0.f, 0.f, 0.f, 0.f, 0.f, 0.f};
    for (int n = 0; n < cN; ++n) {
        float csr = md[n*6+0], csi = md[n*6+1];
        float zr  = md[n*6+2], zi  = md[n*6+3];
        float ar  = md[n*6+4], ai  = md[n*6+5];
        float mag = expf(ar * (float)t0);
        double ph = fmod((double)ai * (double)t0, 6.283185307179586);
        float s, c; sincosf((float)ph, &s, &c);
        float pr = mag * c, pi = mag * s;
#pragma unroll
        for (int i = 0; i < 8; ++i) {
            acc[i] += csr * pr - csi * pi;
            float tr = pr * zr - pi * zi;
            pi = pr * zi + pi * zr;
            pr = tr;
        }
    }
    short8 v;
#pragma unroll
    for (int i = 0; i < 8; ++i) v[i] = f2bf(2.f * acc[i]);
    *reinterpret_cast<short8*>(&Wb[S_A + (size_t)(BH + h) * 2048 + t0]) = v;
}

// ---------------- 256x256 8-phase GEMM core (unchanged, proven r7) ----------
__device__ __forceinline__ void gemm8p_core(
    const short* __restrict__ Ag, int lda,
    const short* __restrict__ Bg, int ldb,
    int m0, int n0, int nt, short* lds, f32x4 (&acc)[4][4][2])
{
    const int tid  = threadIdx.x;
    const int wave = tid >> 6, lane = tid & 63;
    const int wm = wave >> 2, wn = wave & 3;
    const int lm = lane & 15, lk = lane >> 4;
    const int srow8 = lane >> 3;
    const int scol  = (lane & 7) * 8;

    auto stage = [&](const short* G, int ldg, int row0, int half, int kt, int sb) {
        short* l0 = lds + sb + (size_t)((kt & 1) * 2 + half) * 8192;
#pragma unroll
        for (int q = 0; q < 2; ++q) {
            int chunk = wave * 2 + q;
            int r = chunk * 8 + srow8;
            int c = scol ^ ((r & 7) << 3);
            load_lds16(G + (size_t)(row0 + half * 128 + r) * ldg + kt * 64 + c,
                       l0 + chunk * 512);
        }
    };
    auto rdA = [&](int qa, int kt, int mi, int kk) -> short8 {
        int rl = wm * 64 + mi * 16 + lm;
        int c  = (kk * 32 + lk * 8) ^ ((rl & 7) << 3);
        return *(const short8*)(lds + (size_t)((kt & 1) * 2 + qa) * 8192 + rl * 64 + c);
    };
    auto rdB = [&](int qb, int kt, int ni, int kk) -> short8 {
        int rl = wn * 32 + ni * 16 + lm;
        int c  = (kk * 32 + lk * 8) ^ ((rl & 7) << 3);
        return *(const short8*)(lds + 32768 + (size_t)((kt & 1) * 2 + qb) * 8192 + rl * 64 + c);
    };

    stage(Ag, lda, m0, 0, 0, 0);
    stage(Bg, ldb, n0, 0, 0, 32768);
    stage(Bg, ldb, n0, 1, 0, 32768);
    stage(Ag, lda, m0, 1, 0, 0);
    if (nt > 1) { stage(Ag, lda, m0, 0, 1, 0); stage(Bg, ldb, n0, 1, 1, 32768); }
    WAIT_VM(4);
    __builtin_amdgcn_s_barrier();

    short8 a[4][2], b[2][2];
    for (int t = 0; t < nt; ++t) {
        // ---- P0 ----
#pragma unroll
        for (int mi = 0; mi < 4; ++mi) { a[mi][0] = rdA(0, t, mi, 0); a[mi][1] = rdA(0, t, mi, 1); }
#pragma unroll
        for (int ni = 0; ni < 2; ++ni) { b[ni][0] = rdB(0, t, ni, 0); b[ni][1] = rdB(0, t, ni, 1); }
        if (t + 1 < nt) stage(Ag, lda, m0, 1, t + 1, 0);
        __builtin_amdgcn_s_barrier();
        WAIT_LGKM0();
        __builtin_amdgcn_s_setprio(1);
#pragma unroll
        for (int kk = 0; kk < 2; ++kk)
#pragma unroll
        for (int ni = 0; ni < 2; ++ni)
#pragma unroll
        for (int mi = 0; mi < 4; ++mi)
            acc[0][mi][ni] = __builtin_amdgcn_mfma_f32_16x16x32_bf16(a[mi][kk], b[ni][kk], acc[0][mi][ni], 0, 0, 0);
        __builtin_amdgcn_s_setprio(0);
        __builtin_amdgcn_s_barrier();
        // ---- P1 ----
#pragma unroll
        for (int ni = 0; ni < 2; ++ni) { b[ni][0] = rdB(1, t, ni, 0); b[ni][1] = rdB(1, t, ni, 1); }
        if (t + 1 < nt) stage(Bg, ldb, n0, 0, t + 1, 32768);
        __builtin_amdgcn_s_barrier();
        WAIT_LGKM0();
        __builtin_amdgcn_s_setprio(1);
#pragma unroll
        for (int kk = 0; kk < 2; ++kk)
#pragma unroll
        for (int ni = 0; ni < 2; ++ni)
#pragma unroll
        for (int mi = 0; mi < 4; ++mi)
            acc[1][mi][ni] = __builtin_amdgcn_mfma_f32_16x16x32_bf16(a[mi][kk], b[ni][kk], acc[1][mi][ni], 0, 0, 0);
        __builtin_amdgcn_s_setprio(0);
        __builtin_amdgcn_s_barrier();
        // ---- P2 ----
#pragma unroll
        for (int mi = 0; mi < 4; ++mi) { a[mi][0] = rdA(1, t, mi, 0); a[mi][1] = rdA(1, t, mi, 1); }
        if (t + 2 < nt) stage(Ag, lda, m0, 0, t + 2, 0);
        __builtin_amdgcn_s_barrier();
        WAIT_LGKM0();
        __builtin_amdgcn_s_setprio(1);
#pragma unroll
        for (int kk = 0; kk < 2; ++kk)
#pragma unroll
        for (int ni = 0; ni < 2; ++ni)
#pragma unroll
        for (int mi = 0; mi < 4; ++mi)
            acc[3][mi][ni] = __builtin_amdgcn_mfma_f32_16x16x32_bf16(a[mi][kk], b[ni][kk], acc[3][mi][ni], 0, 0, 0);
        __builtin_amdgcn_s_setprio(0);
        __builtin_amdgcn_s_barrier();
        // ---- P3 ----
#pragma unroll
        for (int ni = 0; ni < 2; ++ni) { b[ni][0] = rdB(0, t, ni, 0); b[ni][1] = rdB(0, t, ni, 1); }
        if (t + 2 < nt) stage(Bg, ldb, n0, 1, t + 2, 32768);
        if (t < nt - 2) { WAIT_VM(4); } else { WAIT_VM(0); }
        __builtin_amdgcn_s_barrier();
        WAIT_LGKM0();
        __builtin_amdgcn_s_setprio(1);
#pragma unroll
        for (int kk = 0; kk < 2; ++kk)
#pragma unroll
        for (int ni = 0; ni < 2; ++ni)
#pragma unroll
        for (int mi = 0; mi < 4; ++mi)
            acc[2][mi][ni] = __builtin_amdgcn_mfma_f32_16x16x32_bf16(a[mi][kk], b[ni][kk], acc[2][mi][ni], 0, 0, 0);
        __builtin_amdgcn_s_setprio(0);
        __builtin_amdgcn_s_barrier();
    }
}

// forward: acc = A_u x B1'^T; fused mix epilogue -> Ys (in U region, rows<4096)
__global__ __launch_bounds__(512, 2) void k_fwd8(short* __restrict__ Wb)
{
    __shared__ short lds_s[65536];
    int tile = (blockIdx.x & 7) * 32 + (blockIdx.x >> 3);
    const int m0 = (tile >> 4) * 256, n0 = (tile & 15) * 256;
    const int tid = threadIdx.x;
    const int wave = tid >> 6, lane = tid & 63;
    const int wm = wave >> 2, wn = wave & 3;
    const int lm = lane & 15, lk = lane >> 4;

    f32x4 acc[4][4][2] = {};
    gemm8p_core(Wb + S_A, 2048, Wb + S_B1, 2048, m0, n0, 32, lds_s, acc);

    short* Ys = Wb + S_U;
    const short* KF = Wb + S_U;   // rows 4096+h (written by k_kfg, interleaved)
    short (*M)[136] = (short(*)[136])lds_s;
    for (int q = 0; q < 4; ++q) {
        __syncthreads();
#pragma unroll
        for (int mi = 0; mi < 4; ++mi)
#pragma unroll
        for (int ni = 0; ni < 2; ++ni)
#pragma unroll
        for (int r = 0; r < 4; ++r)
            M[wm * 64 + mi * 16 + lk * 4 + r][wn * 32 + ni * 16 + lm] =
                f2bf(acc[q][mi][ni][r]);
        __syncthreads();
        const int jwin = (n0 >> 1) + (q & 1) * 64;
#pragma unroll
        for (int pass = 0; pass < 4; ++pass) {
            int rl = pass * 32 + (tid >> 4);
            int p0 = (tid & 15) * 4;
            int rowg = m0 + (q >> 1) * 128 + rl;
            int h = rowg & (cH - 1);
            short8 kf8 = *(const short8*)&KF[(size_t)(4096 + h) * 4096 + 2 * (jwin + p0)];
            short8 m8  = *(const short8*)&M[rl][2 * p0];
            sh4 yr4, yi4;
#pragma unroll
            for (int i = 0; i < 4; ++i) {
                float C  = bf2f(m8[2*i]),  S  = bf2f(m8[2*i+1]);
                float Ck = bf2f(kf8[2*i]), Sk = bf2f(kf8[2*i+1]);
                int j = jwin + p0 + i;
                float sc = (j == 0 ? 1.0f : 2.0f) * (1.0f / (float)M2);
                yr4[i] = f2bf(sc * (Ck * C - Sk * S));
                yi4[i] = f2bf(sc * (Ck * S + Sk * C));
            }
            *(sh4*)&Ys[(size_t)rowg * 4096 + jwin + p0]        = yr4;
            *(sh4*)&Ys[(size_t)rowg * 4096 + 2048 + jwin + p0] = yi4;
        }
    }
}

// KF rows: U[4096+h] = A_k x B1'^T  (runs BEFORE k_fwd8)
__global__ __launch_bounds__(256, 2) void k_kfg(short* __restrict__ Wb)
{
    __shared__ __align__(16) short As[128][32];
    __shared__ __align__(16) short Bs[128][32];
    const short* A = Wb + S_A;
    const short* B = Wb + S_B1;
    short* U = Wb + S_U;
    const int tid = threadIdx.x;
    const int m0 = 4096 + blockIdx.y * 128, n0 = blockIdx.x * 128;
    const int wave = tid >> 6, lane = tid & 63;
    const int wr = wave >> 1, wc = wave & 1;
    const int lm = lane & 15, lk = lane >> 4;
    const int srow = lane >> 2, scol = (lane & 3) * 8;

    f32x4 acc[4][4] = {};
    for (int k0 = 0; k0 < 2048; k0 += 32) {
        __syncthreads();
        {
            int c0 = wave * 2;
            load_lds16(&A[(size_t)(m0 + c0*16      + srow)*2048 + k0 + scol], &As[c0*16][0]);
            load_lds16(&A[(size_t)(m0 + c0*16 + 16 + srow)*2048 + k0 + scol], &As[c0*16+16][0]);
            load_lds16(&B[(size_t)(n0 + c0*16      + srow)*2048 + k0 + scol], &Bs[c0*16][0]);
            load_lds16(&B[(size_t)(n0 + c0*16 + 16 + srow)*2048 + k0 + scol], &Bs[c0*16+16][0]);
        }
        __syncthreads();
        short8 a[4];
#pragma unroll
        for (int mi = 0; mi < 4; ++mi)
            a[mi] = *(const short8*)&As[wr*64 + mi*16 + lm][lk*8];
#pragma unroll
        for (int ni = 0; ni < 4; ++ni) {
            short8 b = *(const short8*)&Bs[wc*64 + ni*16 + lm][lk*8];
#pragma unroll
            for (int mi = 0; mi < 4; ++mi)
                acc[mi][ni] = __builtin_amdgcn_mfma_f32_16x16x32_bf16(a[mi], b, acc[mi][ni], 0, 0, 0);
        }
    }
#pragma unroll
    for (int mi = 0; mi < 4; ++mi)
#pragma unroll
    for (int ni = 0; ni < 4; ++ni)
#pragma unroll
    for (int r = 0; r < 4; ++r) {
        int row = m0 + wr*64 + mi*16 + lk*4 + r;
        int col = n0 + wc*64 + ni*16 + lm;
        U[(size_t)row * 4096 + col] = f2bf(acc[mi][ni][r]);
    }
}

// inverse: split-K=2, 8-phase. pass0 -> out (+skip), pass1 -> P1 (B1 region)
__global__ __launch_bounds__(512, 2) void k_inv8(const float* __restrict__ u,
                                                 const float* __restrict__ Dp,
                                                 short* __restrict__ Wb,
                                                 float* __restrict__ out)
{
    __shared__ short lds_s[65536];
    int tile = (blockIdx.x & 7) * 32 + (blockIdx.x >> 3);
    const int pass = tile >> 7;
    const int rem  = tile & 127;
    const int m0 = (rem >> 3) * 256, n0 = (rem & 7) * 256;
    const int tid = threadIdx.x;
    const int wave = tid >> 6, lane = tid & 63;
    const int wm = wave >> 2, wn = wave & 3;
    const int lm = lane & 15, lk = lane >> 4;

    f32x4 acc[4][4][2] = {};
    const short* Ag = Wb + S_U  + pass * 2048;
    const short* Bg = Wb + S_T2 + pass * 2048;
    gemm8p_core(Ag, 4096, Bg, 4096, m0, n0, 32, lds_s, acc);

    float* P1 = (float*)(Wb + S_B1);
    const int b  = m0 >> 9;
    const int h0 = m0 & 511;
    float (*T)[132] = (float(*)[132])lds_s;
    const int trow2 = tid >> 5;          // 0..15
    const int hch   = (tid & 31) * 4;    // 0..124
#pragma unroll
    for (int q = 0; q < 4; ++q) {
        __syncthreads();
#pragma unroll
        for (int mi = 0; mi < 4; ++mi)
#pragma unroll
        for (int ni = 0; ni < 2; ++ni) {
            int tl = wn * 32 + ni * 16 + lm;
            int hl = wm * 64 + mi * 16 + lk * 4;
            *(float4*)&T[tl][hl] = *(float4*)&acc[q][mi][ni];
        }
        __syncthreads();
        int hg = h0 + (q >> 1) * 128 + hch;
        float4 dv = *(const float4*)&Dp[hg];
#pragma unroll
        for (int it = 0; it < 8; ++it) {
            int tl = trow2 + it * 16;
            int tg = n0 + (q & 1) * 128 + tl;
            size_t gidx = ((size_t)b * cL + tg) * cH + hg;
            float4 yv = *(float4*)&T[tl][hch];
            if (pass == 0) {
                float4 uv = *(const float4*)&u[gidx];
                yv.x += dv.x * uv.x;
                yv.y += dv.y * uv.y;
                yv.z += dv.z * uv.z;
                yv.w += dv.w * uv.w;
                *(float4*)&out[gidx] = yv;
            } else {
                *(float4*)&P1[gidx] = yv;
            }
        }
    }
}

// out += P1
__global__ __launch_bounds__(256) void k_comb(float* __restrict__ out,
                                              const float* __restrict__ P1)
{
    int i = blockIdx.x * 256 + threadIdx.x;
#pragma unroll
    for (int v = 0; v < 4; ++v) {
        size_t idx = ((size_t)v * 524288 + i) * 4;
        float4 a = *(float4*)&out[idx];
        float4 p = *(const float4*)&P1[idx];
        a.x += p.x; a.y += p.y; a.z += p.z; a.w += p.w;
        *(float4*)&out[idx] = a;
    }
}

extern "C" void kernel_launch(void* const* d_in, const int* in_sizes, int n_in,
                              void* d_out, int out_size, void* d_ws, size_t ws_size,
                              hipStream_t stream) {
    const float* u    = (const float*)d_in[0];
    const float* w_re = (const float*)d_in[1];
    const float* w_im = (const float*)d_in[2];
    const float* C_re = (const float*)d_in[3];
    const float* C_im = (const float*)d_in[4];
    const float* Dp   = (const float*)d_in[5];
    const float* dt   = (const float*)d_in[6];
    float* out = (float*)d_out;
    float* Wf  = (float*)d_ws;
    short* Wb  = (short*)d_ws;

    hipLaunchKernelGGL(k_precomp, dim3((cH * cN + 255) / 256), dim3(256), 0, stream,
                       w_re, w_im, C_re, C_im, dt, Wf);
    hipLaunchKernelGGL(k_tab1,  dim3(2048), dim3(256), 0, stream, Wb);
    hipLaunchKernelGGL(k_tab2,  dim3(2048), dim3(256), 0, stream, Wb);
    hipLaunchKernelGGL(k_trans, dim3(cL / 64, cH / 64, cB), dim3(256), 0, stream, u, Wb);
    hipLaunchKernelGGL(k_kgen,  dim3(cH), dim3(256), 0, stream, Wf, Wb);
    hipLaunchKernelGGL(k_kfg,   dim3(32, 4), dim3(256), 0, stream, Wb);
    hipLaunchKernelGGL(k_fwd8,  dim3(256), dim3(512), 0, stream, Wb);
    hipLaunchKernelGGL(k_inv8,  dim3(256), dim3(512), 0, stream, u, Dp, Wb, out);
    hipLaunchKernelGGL(k_comb,  dim3(2048), dim3(256), 0, stream, out, (const float*)(Wb + S_B1));
}

// Round 9
// 228.422 us; speedup vs baseline: 1.3606x; 1.0949x over previous
//
#include <hip/hip_runtime.h>
#include <hip/hip_bf16.h>
#include <math.h>

// S4DConv via MFMA: B=8, L=2048, H=512, N=64, CH=1
//   k_tabs:  B1' interleaved cos/sin [4096][2048] + T2 [2048][4096]
//   k_trans: A u-rows [4096][2048] bf16 ; k_kgen: A k-rows (precomp inlined)
//   k_kfg:   KF rows = A_k x B1'^T -> U rows 4096+
//   k_fwd8:  256^2 8-phase GEMM, epilogue fuses complex mix -> Ys (U rows <4096)
//   k_invB:  single-pass 256x128 2-phase GEMM y = Ys x T2^T (K=4096), fused skip

namespace {
constexpr int cB = 8;
constexpr int cL = 2048;
constexpr int cH = 512;
constexpr int cN = 64;
constexpr int M1 = 4095;
constexpr int M2 = 4096;
constexpr int BH = cB * cH;            // 4096
constexpr int MA = BH + cH;            // 4608

constexpr size_t S0   = 2 * ((size_t)cH * cN * 6);
constexpr size_t S_B1 = S0;                           // [4096][2048] interleaved
constexpr size_t S_A  = S_B1 + (size_t)4096 * 2048;   // [4608][2048]
constexpr size_t S_T2 = S_A  + (size_t)MA * 2048;     // [2048][4096]
constexpr size_t S_U  = S_T2 + (size_t)2048 * 4096;   // [4608][4096]: rows<4096 Ys; 4096+ KF
}

typedef __attribute__((ext_vector_type(8))) short short8;
typedef __attribute__((ext_vector_type(4))) short sh4;
typedef __attribute__((ext_vector_type(4))) float f32x4;

static __device__ inline short f2bf(float x) {
    __hip_bfloat16 h = __float2bfloat16(x);
    return *reinterpret_cast<short*>(&h);
}
static __device__ inline float bf2f(short s) {
    return __uint_as_float(((unsigned int)(unsigned short)s) << 16);
}
static __device__ __forceinline__ void load_lds16(const short* g, short* l) {
    __builtin_amdgcn_global_load_lds(
        (const __attribute__((address_space(1))) void*)g,
        (__attribute__((address_space(3))) void*)l, 16, 0, 0);
}
#define WAIT_LGKM0() do { asm volatile("s_waitcnt lgkmcnt(0)" ::: "memory"); \
                          __builtin_amdgcn_sched_barrier(0); } while (0)
#define WAIT_VM(n)   do { asm volatile("s_waitcnt vmcnt(" #n ")" ::: "memory"); \
                          __builtin_amdgcn_sched_barrier(0); } while (0)

// B1'[2j][t]=cos(2pi jt/4095), B1'[2j+1][t]=sin  (blocks 0..2047)
// T2[t][j]=cos(2pi tj/4096), T2[t][2048+j]=sin   (blocks 2048..4095)
__global__ __launch_bounds__(256) void k_tabs(short* __restrict__ Wb)
{
    if (blockIdx.x < 2048) {
        int j  = blockIdx.x;
        int t0 = threadIdx.x * 8;
        int p  = (int)(((long)j * t0) % M1);
        short8 vc, vs;
#pragma unroll
        for (int i = 0; i < 8; ++i) {
            float s, c;
            sincosf((6.283185307179586f / (float)M1) * (float)p, &s, &c);
            vc[i] = f2bf(c); vs[i] = f2bf(s);
            p += j; if (p >= M1) p -= M1;
        }
        *(short8*)&Wb[S_B1 + (size_t)(2 * j)     * 2048 + t0] = vc;
        *(short8*)&Wb[S_B1 + (size_t)(2 * j + 1) * 2048 + t0] = vs;
    } else {
        int t  = blockIdx.x - 2048;
        int j0 = threadIdx.x * 8;
        int p  = (t * j0) & (M2 - 1);
        short8 vc, vs;
#pragma unroll
        for (int i = 0; i < 8; ++i) {
            float s, c;
            sincosf((6.283185307179586f / (float)M2) * (float)p, &s, &c);
            vc[i] = f2bf(c); vs[i] = f2bf(s);
            p = (p + t) & (M2 - 1);
        }
        *(short8*)&Wb[S_T2 + (size_t)t * 4096 + j0]        = vc;
        *(short8*)&Wb[S_T2 + (size_t)t * 4096 + 2048 + j0] = vs;
    }
}

__global__ __launch_bounds__(256) void k_trans(const float* __restrict__ u,
                                               short* __restrict__ Wb)
{
    __shared__ float tile[64][65];
    int t0 = blockIdx.x * 64;
    int h0 = blockIdx.y * 64;
    int b  = blockIdx.z;
    int cx = threadIdx.x & 63, r0 = threadIdx.x >> 6;
#pragma unroll
    for (int i = 0; i < 16; ++i) {
        int row = r0 + i * 4;
        tile[row][cx] = u[((size_t)b * cL + t0 + row) * cH + h0 + cx];
    }
    __syncthreads();
    short* A = Wb + S_A;
#pragma unroll
    for (int i = 0; i < 16; ++i) {
        int hrow = r0 + i * 4;
        A[(size_t)(b * cH + h0 + hrow) * 2048 + t0 + cx] = f2bf(tile[cx][hrow]);
    }
}

// A'[4096+h][t] = bf16(k[h][t]); per-h mode precompute inlined (threads 0..63)
__global__ __launch_bounds__(256) void k_kgen(
    const float* __restrict__ w_re, const float* __restrict__ w_im,
    const float* __restrict__ C_re, const float* __restrict__ C_im,
    const float* __restrict__ dt, short* __restrict__ Wb)
{
    __shared__ float md[cN * 6];
    int h = blockIdx.x, tid = threadIdx.x;
    if (tid < cN) {
        int idx = h * cN + tid;
        double dtv = dt[h];
        double wr = w_re[idx], wi = w_im[idx];
        double ar = wr * dtv, ai = wi * dtv;
        double er = exp(ar);
        double zs, zc; sincos(ai, &zs, &zc);
        double zr = er * zc, zi = er * zs;
        double nr = zr - 1.0, ni = zi;
        double inv = 1.0 / (wr * wr + wi * wi);
        double gr = (nr * wr + ni * wi) * inv;
        double gi = (ni * wr - nr * wi) * inv;
        double cr = C_re[idx], ci = C_im[idx];
        md[tid*6+0] = (float)(cr * gr - ci * gi);
        md[tid*6+1] = (float)(cr * gi + ci * gr);
        md[tid*6+2] = (float)zr; md[tid*6+3] = (float)zi;
        md[tid*6+4] = (float)ar; md[tid*6+5] = (float)ai;
    }
    __syncthreads();
    int t0 = tid * 8;
    float acc[8] = {0.f, 0.f, 0.f, 0.f, 0.f, 0.f, 0.f, 0.f};
    for (int n = 0; n < cN; ++n) {
        float csr = md[n*6+0], csi = md[n*6+1];
        float zr  = md[n*6+2], zi  = md[n*6+3];
        float ar  = md[n*6+4], ai  = md[n*6+5];
        float mag = expf(ar * (float)t0);
        double ph = fmod((double)ai * (double)t0, 6.283185307179586);
        float s, c; sincosf((float)ph, &s, &c);
        float pr = mag * c, pi = mag * s;
#pragma unroll
        for (int i = 0; i < 8; ++i) {
            acc[i] += csr * pr - csi * pi;
            float tr = pr * zr - pi * zi;
            pi = pr * zi + pi * zr;
            pr = tr;
        }
    }
    short8 v;
#pragma unroll
    for (int i = 0; i < 8; ++i) v[i] = f2bf(2.f * acc[i]);
    *reinterpret_cast<short8*>(&Wb[S_A + (size_t)(BH + h) * 2048 + t0]) = v;
}

// ---------------- 256x256 8-phase GEMM core (proven r7/r8) ------------------
__device__ __forceinline__ void gemm8p_core(
    const short* __restrict__ Ag, int lda,
    const short* __restrict__ Bg, int ldb,
    int m0, int n0, int nt, short* lds, f32x4 (&acc)[4][4][2])
{
    const int tid  = threadIdx.x;
    const int wave = tid >> 6, lane = tid & 63;
    const int wm = wave >> 2, wn = wave & 3;
    const int lm = lane & 15, lk = lane >> 4;
    const int srow8 = lane >> 3;
    const int scol  = (lane & 7) * 8;

    auto stage = [&](const short* G, int ldg, int row0, int half, int kt, int sb) {
        short* l0 = lds + sb + (size_t)((kt & 1) * 2 + half) * 8192;
#pragma unroll
        for (int q = 0; q < 2; ++q) {
            int chunk = wave * 2 + q;
            int r = chunk * 8 + srow8;
            int c = scol ^ ((r & 7) << 3);
            load_lds16(G + (size_t)(row0 + half * 128 + r) * ldg + kt * 64 + c,
                       l0 + chunk * 512);
        }
    };
    auto rdA = [&](int qa, int kt, int mi, int kk) -> short8 {
        int rl = wm * 64 + mi * 16 + lm;
        int c  = (kk * 32 + lk * 8) ^ ((rl & 7) << 3);
        return *(const short8*)(lds + (size_t)((kt & 1) * 2 + qa) * 8192 + rl * 64 + c);
    };
    auto rdB = [&](int qb, int kt, int ni, int kk) -> short8 {
        int rl = wn * 32 + ni * 16 + lm;
        int c  = (kk * 32 + lk * 8) ^ ((rl & 7) << 3);
        return *(const short8*)(lds + 32768 + (size_t)((kt & 1) * 2 + qb) * 8192 + rl * 64 + c);
    };

    stage(Ag, lda, m0, 0, 0, 0);
    stage(Bg, ldb, n0, 0, 0, 32768);
    stage(Bg, ldb, n0, 1, 0, 32768);
    stage(Ag, lda, m0, 1, 0, 0);
    if (nt > 1) { stage(Ag, lda, m0, 0, 1, 0); stage(Bg, ldb, n0, 1, 1, 32768); }
    WAIT_VM(4);
    __builtin_amdgcn_s_barrier();

    short8 a[4][2], b[2][2];
    for (int t = 0; t < nt; ++t) {
        // ---- P0 ----
#pragma unroll
        for (int mi = 0; mi < 4; ++mi) { a[mi][0] = rdA(0, t, mi, 0); a[mi][1] = rdA(0, t, mi, 1); }
#pragma unroll
        for (int ni = 0; ni < 2; ++ni) { b[ni][0] = rdB(0, t, ni, 0); b[ni][1] = rdB(0, t, ni, 1); }
        if (t + 1 < nt) stage(Ag, lda, m0, 1, t + 1, 0);
        __builtin_amdgcn_s_barrier();
        WAIT_LGKM0();
        __builtin_amdgcn_s_setprio(1);
#pragma unroll
        for (int kk = 0; kk < 2; ++kk)
#pragma unroll
        for (int ni = 0; ni < 2; ++ni)
#pragma unroll
        for (int mi = 0; mi < 4; ++mi)
            acc[0][mi][ni] = __builtin_amdgcn_mfma_f32_16x16x32_bf16(a[mi][kk], b[ni][kk], acc[0][mi][ni], 0, 0, 0);
        __builtin_amdgcn_s_setprio(0);
        __builtin_amdgcn_s_barrier();
        // ---- P1 ----
#pragma unroll
        for (int ni = 0; ni < 2; ++ni) { b[ni][0] = rdB(1, t, ni, 0); b[ni][1] = rdB(1, t, ni, 1); }
        if (t + 1 < nt) stage(Bg, ldb, n0, 0, t + 1, 32768);
        __builtin_amdgcn_s_barrier();
        WAIT_LGKM0();
        __builtin_amdgcn_s_setprio(1);
#pragma unroll
        for (int kk = 0; kk < 2; ++kk)
#pragma unroll
        for (int ni = 0; ni < 2; ++ni)
#pragma unroll
        for (int mi = 0; mi < 4; ++mi)
            acc[1][mi][ni] = __builtin_amdgcn_mfma_f32_16x16x32_bf16(a[mi][kk], b[ni][kk], acc[1][mi][ni], 0, 0, 0);
        __builtin_amdgcn_s_setprio(0);
        __builtin_amdgcn_s_barrier();
        // ---- P2 ----
#pragma unroll
        for (int mi = 0; mi < 4; ++mi) { a[mi][0] = rdA(1, t, mi, 0); a[mi][1] = rdA(1, t, mi, 1); }
        if (t + 2 < nt) stage(Ag, lda, m0, 0, t + 2, 0);
        __builtin_amdgcn_s_barrier();
        WAIT_LGKM0();
        __builtin_amdgcn_s_setprio(1);
#pragma unroll
        for (int kk = 0; kk < 2; ++kk)
#pragma unroll
        for (int ni = 0; ni < 2; ++ni)
#pragma unroll
        for (int mi = 0; mi < 4; ++mi)
            acc[3][mi][ni] = __builtin_amdgcn_mfma_f32_16x16x32_bf16(a[mi][kk], b[ni][kk], acc[3][mi][ni], 0, 0, 0);
        __builtin_amdgcn_s_setprio(0);
        __builtin_amdgcn_s_barrier();
        // ---- P3 ----
#pragma unroll
        for (int ni = 0; ni < 2; ++ni) { b[ni][0] = rdB(0, t, ni, 0); b[ni][1] = rdB(0, t, ni, 1); }
        if (t + 2 < nt) stage(Bg, ldb, n0, 1, t + 2, 32768);
        if (t < nt - 2) { WAIT_VM(4); } else { WAIT_VM(0); }
        __builtin_amdgcn_s_barrier();
        WAIT_LGKM0();
        __builtin_amdgcn_s_setprio(1);
#pragma unroll
        for (int kk = 0; kk < 2; ++kk)
#pragma unroll
        for (int ni = 0; ni < 2; ++ni)
#pragma unroll
        for (int mi = 0; mi < 4; ++mi)
            acc[2][mi][ni] = __builtin_amdgcn_mfma_f32_16x16x32_bf16(a[mi][kk], b[ni][kk], acc[2][mi][ni], 0, 0, 0);
        __builtin_amdgcn_s_setprio(0);
        __builtin_amdgcn_s_barrier();
    }
}

// forward: acc = A_u x B1'^T; fused mix epilogue -> Ys (U region rows<4096)
__global__ __launch_bounds__(512, 2) void k_fwd8(short* __restrict__ Wb)
{
    __shared__ short lds_s[65536];
    int tile = (blockIdx.x & 7) * 32 + (blockIdx.x >> 3);
    const int m0 = (tile >> 4) * 256, n0 = (tile & 15) * 256;
    const int tid = threadIdx.x;
    const int wave = tid >> 6, lane = tid & 63;
    const int wm = wave >> 2, wn = wave & 3;
    const int lm = lane & 15, lk = lane >> 4;

    f32x4 acc[4][4][2] = {};
    gemm8p_core(Wb + S_A, 2048, Wb + S_B1, 2048, m0, n0, 32, lds_s, acc);

    short* Ys = Wb + S_U;
    const short* KF = Wb + S_U;
    short (*M)[136] = (short(*)[136])lds_s;
    for (int q = 0; q < 4; ++q) {
        __syncthreads();
#pragma unroll
        for (int mi = 0; mi < 4; ++mi)
#pragma unroll
        for (int ni = 0; ni < 2; ++ni)
#pragma unroll
        for (int r = 0; r < 4; ++r)
            M[wm * 64 + mi * 16 + lk * 4 + r][wn * 32 + ni * 16 + lm] =
                f2bf(acc[q][mi][ni][r]);
        __syncthreads();
        const int jwin = (n0 >> 1) + (q & 1) * 64;
#pragma unroll
        for (int pass = 0; pass < 4; ++pass) {
            int rl = pass * 32 + (tid >> 4);
            int p0 = (tid & 15) * 4;
            int rowg = m0 + (q >> 1) * 128 + rl;
            int h = rowg & (cH - 1);
            short8 kf8 = *(const short8*)&KF[(size_t)(4096 + h) * 4096 + 2 * (jwin + p0)];
            short8 m8  = *(const short8*)&M[rl][2 * p0];
            sh4 yr4, yi4;
#pragma unroll
            for (int i = 0; i < 4; ++i) {
                float C  = bf2f(m8[2*i]),  S  = bf2f(m8[2*i+1]);
                float Ck = bf2f(kf8[2*i]), Sk = bf2f(kf8[2*i+1]);
                int j = jwin + p0 + i;
                float sc = (j == 0 ? 1.0f : 2.0f) * (1.0f / (float)M2);
                yr4[i] = f2bf(sc * (Ck * C - Sk * S));
                yi4[i] = f2bf(sc * (Ck * S + Sk * C));
            }
            *(sh4*)&Ys[(size_t)rowg * 4096 + jwin + p0]        = yr4;
            *(sh4*)&Ys[(size_t)rowg * 4096 + 2048 + jwin + p0] = yi4;
        }
    }
}

// KF rows: U[4096+h] = A_k x B1'^T
__global__ __launch_bounds__(256, 2) void k_kfg(short* __restrict__ Wb)
{
    __shared__ __align__(16) short As[128][32];
    __shared__ __align__(16) short Bs[128][32];
    const short* A = Wb + S_A;
    const short* B = Wb + S_B1;
    short* U = Wb + S_U;
    const int tid = threadIdx.x;
    const int m0 = 4096 + blockIdx.y * 128, n0 = blockIdx.x * 128;
    const int wave = tid >> 6, lane = tid & 63;
    const int wr = wave >> 1, wc = wave & 1;
    const int lm = lane & 15, lk = lane >> 4;
    const int srow = lane >> 2, scol = (lane & 3) * 8;

    f32x4 acc[4][4] = {};
    for (int k0 = 0; k0 < 2048; k0 += 32) {
        __syncthreads();
        {
            int c0 = wave * 2;
            load_lds16(&A[(size_t)(m0 + c0*16      + srow)*2048 + k0 + scol], &As[c0*16][0]);
            load_lds16(&A[(size_t)(m0 + c0*16 + 16 + srow)*2048 + k0 + scol], &As[c0*16+16][0]);
            load_lds16(&B[(size_t)(n0 + c0*16      + srow)*2048 + k0 + scol], &Bs[c0*16][0]);
            load_lds16(&B[(size_t)(n0 + c0*16 + 16 + srow)*2048 + k0 + scol], &Bs[c0*16+16][0]);
        }
        __syncthreads();
        short8 a[4];
#pragma unroll
        for (int mi = 0; mi < 4; ++mi)
            a[mi] = *(const short8*)&As[wr*64 + mi*16 + lm][lk*8];
#pragma unroll
        for (int ni = 0; ni < 4; ++ni) {
            short8 b = *(const short8*)&Bs[wc*64 + ni*16 + lm][lk*8];
#pragma unroll
            for (int mi = 0; mi < 4; ++mi)
                acc[mi][ni] = __builtin_amdgcn_mfma_f32_16x16x32_bf16(a[mi], b, acc[mi][ni], 0, 0, 0);
        }
    }
#pragma unroll
    for (int mi = 0; mi < 4; ++mi)
#pragma unroll
    for (int ni = 0; ni < 4; ++ni)
#pragma unroll
    for (int r = 0; r < 4; ++r) {
        int row = m0 + wr*64 + mi*16 + lk*4 + r;
        int col = n0 + wc*64 + ni*16 + lm;
        U[(size_t)row * 4096 + col] = f2bf(acc[mi][ni][r]);
    }
}

// inverse: single pass, BM=256(bh) x BN=128(t), BK=64, K=4096, 2-phase
// LDS: A units ((kt&1)*2+half)*8192 shorts (64KB), B 32768+(kt&1)*8192 (32KB)
// vmcnt ledger (steady): P0 stages B(t+1); P1 stages A0/A1(t+1);
//   each phase ends vmcnt(2) -> exactly A1(t+1) (the pair needed 2 phases
//   later) stays in flight. Last tile's P0 drains with vmcnt(0).
__global__ __launch_bounds__(512, 1) void k_invB(const float* __restrict__ u,
                                                 const float* __restrict__ Dp,
                                                 short* __restrict__ Wb,
                                                 float* __restrict__ out)
{
    __shared__ short lds_s[49152];   // 96 KB
    int tile = (blockIdx.x & 7) * 32 + (blockIdx.x >> 3);
    const int m0 = (tile >> 4) * 256;   // bh
    const int n0 = (tile & 15) * 128;   // t
    const int tid = threadIdx.x;
    const int wave = tid >> 6, lane = tid & 63;
    const int wm = wave >> 2, wn = wave & 3;
    const int lm = lane & 15, lk = lane >> 4;
    const int srow8 = lane >> 3;
    const int scol  = (lane & 7) * 8;
    constexpr int nt = 64;
    short* lds = lds_s;
    const short* Ag = Wb + S_U;    // Ys [4096][4096]
    const short* Bg = Wb + S_T2;   // [2048][4096]

    auto stageA = [&](int half, int kt) {
        short* l0 = lds + (size_t)((kt & 1) * 2 + half) * 8192;
#pragma unroll
        for (int q = 0; q < 2; ++q) {
            int chunk = wave * 2 + q;
            int r = chunk * 8 + srow8;
            int c = scol ^ ((r & 7) << 3);
            load_lds16(Ag + (size_t)(m0 + half * 128 + r) * 4096 + kt * 64 + c,
                       l0 + chunk * 512);
        }
    };
    auto stageB = [&](int kt) {
        short* l0 = lds + 32768 + (size_t)(kt & 1) * 8192;
#pragma unroll
        for (int q = 0; q < 2; ++q) {
            int chunk = wave * 2 + q;
            int r = chunk * 8 + srow8;
            int c = scol ^ ((r & 7) << 3);
            load_lds16(Bg + (size_t)(n0 + r) * 4096 + kt * 64 + c,
                       l0 + chunk * 512);
        }
    };
    auto rdA = [&](int half, int kt, int mi, int kk) -> short8 {
        int rl = wm * 64 + mi * 16 + lm;
        int c  = (kk * 32 + lk * 8) ^ ((rl & 7) << 3);
        return *(const short8*)(lds + (size_t)((kt & 1) * 2 + half) * 8192 + rl * 64 + c);
    };
    auto rdB = [&](int kt, int ni, int kk) -> short8 {
        int rl = wn * 32 + ni * 16 + lm;
        int c  = (kk * 32 + lk * 8) ^ ((rl & 7) << 3);
        return *(const short8*)(lds + 32768 + (size_t)(kt & 1) * 8192 + rl * 64 + c);
    };

    f32x4 acc[2][4][2] = {};

    // prologue: A0(0), B(0), A1(0); retire first two, keep A1(0) in flight
    stageA(0, 0);
    stageB(0);
    stageA(1, 0);
    WAIT_VM(2);
    __builtin_amdgcn_s_barrier();

    short8 a[4][2], b[2][2];
    for (int t = 0; t < nt; ++t) {
        // ---- P0: A0 x B ----
#pragma unroll
        for (int mi = 0; mi < 4; ++mi) { a[mi][0] = rdA(0, t, mi, 0); a[mi][1] = rdA(0, t, mi, 1); }
#pragma unroll
        for (int ni = 0; ni < 2; ++ni) { b[ni][0] = rdB(t, ni, 0); b[ni][1] = rdB(t, ni, 1); }
        if (t + 1 < nt) stageB(t + 1);
        __builtin_amdgcn_s_barrier();
        WAIT_LGKM0();
        __builtin_amdgcn_s_setprio(1);
#pragma unroll
        for (int kk = 0; kk < 2; ++kk)
#pragma unroll
        for (int ni = 0; ni < 2; ++ni)
#pragma unroll
        for (int mi = 0; mi < 4; ++mi)
            acc[0][mi][ni] = __builtin_amdgcn_mfma_f32_16x16x32_bf16(a[mi][kk], b[ni][kk], acc[0][mi][ni], 0, 0, 0);
        __builtin_amdgcn_s_setprio(0);
        if (t + 1 < nt) { WAIT_VM(2); } else { WAIT_VM(0); }
        __builtin_amdgcn_s_barrier();
        // ---- P1: A1 x B (b held) ----
#pragma unroll
        for (int mi = 0; mi < 4; ++mi) { a[mi][0] = rdA(1, t, mi, 0); a[mi][1] = rdA(1, t, mi, 1); }
        if (t + 1 < nt) { stageA(0, t + 1); stageA(1, t + 1); }
        __builtin_amdgcn_s_barrier();
        WAIT_LGKM0();
        __builtin_amdgcn_s_setprio(1);
#pragma unroll
        for (int kk = 0; kk < 2; ++kk)
#pragma unroll
        for (int ni = 0; ni < 2; ++ni)
#pragma unroll
        for (int mi = 0; mi < 4; ++mi)
            acc[1][mi][ni] = __builtin_amdgcn_mfma_f32_16x16x32_bf16(a[mi][kk], b[ni][kk], acc[1][mi][ni], 0, 0, 0);
        __builtin_amdgcn_s_setprio(0);
        WAIT_VM(2);
        __builtin_amdgcn_s_barrier();
    }

    // epilogue: transpose via LDS; coalesced 512B-run stores; fused skip
    const int b_  = m0 >> 9;
    const int h00 = m0 & 511;
    float (*T)[132] = (float(*)[132])lds_s;
#pragma unroll
    for (int q = 0; q < 2; ++q) {
        __syncthreads();
#pragma unroll
        for (int mi = 0; mi < 4; ++mi)
#pragma unroll
        for (int ni = 0; ni < 2; ++ni) {
            int tl = wn * 32 + ni * 16 + lm;
            int hl = wm * 64 + mi * 16 + lk * 4;
            *(float4*)&T[tl][hl] = *(float4*)&acc[q][mi][ni];
        }
        __syncthreads();
        int hg = h00 + q * 128 + (tid & 31) * 4;
        float4 dv = *(const float4*)&Dp[hg];
#pragma unroll
        for (int it = 0; it < 8; ++it) {
            int tl = (tid >> 5) + it * 16;
            int tg = n0 + tl;
            size_t gidx = ((size_t)b_ * cL + tg) * cH + hg;
            float4 uv = *(const float4*)&u[gidx];
            float4 yv = *(float4*)&T[tl][(tid & 31) * 4];
            yv.x += dv.x * uv.x;
            yv.y += dv.y * uv.y;
            yv.z += dv.z * uv.z;
            yv.w += dv.w * uv.w;
            *(float4*)&out[gidx] = yv;
        }
    }
}

extern "C" void kernel_launch(void* const* d_in, const int* in_sizes, int n_in,
                              void* d_out, int out_size, void* d_ws, size_t ws_size,
                              hipStream_t stream) {
    const float* u    = (const float*)d_in[0];
    const float* w_re = (const float*)d_in[1];
    const float* w_im = (const float*)d_in[2];
    const float* C_re = (const float*)d_in[3];
    const float* C_im = (const float*)d_in[4];
    const float* Dp   = (const float*)d_in[5];
    const float* dt   = (const float*)d_in[6];
    float* out = (float*)d_out;
    short* Wb  = (short*)d_ws;

    hipLaunchKernelGGL(k_tabs,  dim3(4096), dim3(256), 0, stream, Wb);
    hipLaunchKernelGGL(k_trans, dim3(cL / 64, cH / 64, cB), dim3(256), 0, stream, u, Wb);
    hipLaunchKernelGGL(k_kgen,  dim3(cH), dim3(256), 0, stream,
                       w_re, w_im, C_re, C_im, dt, Wb);
    hipLaunchKernelGGL(k_kfg,   dim3(32, 4), dim3(256), 0, stream, Wb);
    hipLaunchKernelGGL(k_fwd8,  dim3(256), dim3(512), 0, stream, Wb);
    hipLaunchKernelGGL(k_invB,  dim3(256), dim3(512), 0, stream, u, Dp, Wb, out);
}